// Round 2
// baseline (1681.448 us; speedup 1.0000x reference)
//
#include <hip/hip_runtime.h>

#define Bdim 8
#define Cdim 64
#define Ndim 4096
#define Kdim 32
#define ROWS (Bdim*Ndim)   /* 32768 */
#define BN_EPS 1e-5f

__device__ __forceinline__ float dot4(float4 a, float4 b){
  return a.x*b.x + a.y*b.y + a.z*b.z + a.w*b.w;
}
// XOR-swizzled weight tile layout: element (o, c) of a 64x64 tile lives at
// o*64 + 4*((c>>2) ^ ((o>>2)&7)) + (c&3).  Reading float4 granule (o, g) with
// lanes varying o by 4 gives conflict-free LDS access (2-way max).
__device__ __forceinline__ int wofs(int o, int g){ return o*64 + (((g ^ ((o>>2)&7)))<<2); }
// order-preserving float->uint key (larger float <=> larger key)
__device__ __forceinline__ unsigned keyOf(float f){
  unsigned u = __float_as_uint(f);
  return (u & 0x80000000u) ? ~u : (u ^ 0x80000000u);
}

// ---------------------------------------------------------------- prep
// x (B,C,N) fp32 -> feat (B,N,C) fp32, sq[b,n] = sum_c feat^2
__global__ __launch_bounds__(256) void prep_kernel(const float* __restrict__ x,
    float* __restrict__ feat, float* __restrict__ sq)
{
  __shared__ float tile[64*65];
  const int tid = threadIdx.x;
  const int b = blockIdx.y;
  const int n0 = blockIdx.x*64;
  for (int k=0;k<16;++k){
    int idx = tid + (k<<8);
    int c = idx>>6, nn = idx&63;
    tile[nn*65+c] = x[((size_t)b*64+c)*Ndim + n0 + nn];
  }
  __syncthreads();
  for (int k=0;k<16;++k){
    int idx = tid + (k<<8);
    int r = idx>>6, c = idx&63;
    feat[((size_t)b*Ndim + n0 + r)*64 + c] = tile[r*65+c];
  }
  if (tid < 64){
    float a = 0.f;
    #pragma unroll
    for (int c=0;c<64;++c){ float v = tile[tid*65+c]; a += v*v; }
    sq[b*Ndim + n0 + tid] = a;
  }
}

// ---------------------------------------------------------------- proj
// Q = feat@wq^T, PK = feat@wk^T, PV = feat@wv^T   (rows=32768, 64x64 weights)
__global__ __launch_bounds__(256) void proj_kernel(const float* __restrict__ feat,
    const float* __restrict__ wq, const float* __restrict__ wk,
    const float* __restrict__ wv,
    float* __restrict__ Qo, float* __restrict__ PKo, float* __restrict__ PVo)
{
  __shared__ __align__(16) float ftile[64*68];
  __shared__ __align__(16) float Ws[3][64*64];
  const int tid = threadIdx.x;
  const size_t rowBase = (size_t)blockIdx.x*64;
  for (int k=0;k<16;++k){
    int idx = tid + (k<<8);
    int r = idx>>6, c = idx&63;
    ftile[r*68+c] = feat[(rowBase + r)*64 + c];
  }
  {
    const float* wp[3] = {wq, wk, wv};
    for (int m=0;m<3;++m)
      for (int k=0;k<16;++k){
        int idx = tid + (k<<8);
        int o = idx>>6, c = idx&63;
        Ws[m][wofs(o, c>>2) + (c&3)] = wp[m][o*64 + c];
      }
  }
  __syncthreads();
  const int tr = tid>>4, to = tid&15;
  float* outp[3] = {Qo, PKo, PVo};
  for (int m=0;m<3;++m){
    float acc[4][4];
    #pragma unroll
    for (int r=0;r<4;++r){ acc[r][0]=0.f; acc[r][1]=0.f; acc[r][2]=0.f; acc[r][3]=0.f; }
    #pragma unroll 4
    for (int c4=0;c4<16;++c4){
      float4 f[4], w[4];
      #pragma unroll
      for (int r=0;r<4;++r)  f[r] = *(const float4*)&ftile[(4*tr+r)*68 + (c4<<2)];
      #pragma unroll
      for (int oo=0;oo<4;++oo) w[oo] = *(const float4*)&Ws[m][wofs(4*to+oo, c4)];
      #pragma unroll
      for (int r=0;r<4;++r)
        #pragma unroll
        for (int oo=0;oo<4;++oo)
          acc[r][oo] += dot4(f[r], w[oo]);
    }
    #pragma unroll
    for (int r=0;r<4;++r){
      float4 v; v.x=acc[r][0]; v.y=acc[r][1]; v.z=acc[r][2]; v.w=acc[r][3];
      *(float4*)&outp[m][(rowBase + 4*tr + r)*64 + 4*to] = v;
    }
  }
}

// ---------------------------------------------------------------- knn + attention
// one workgroup handles 4 query rows of one batch: exact top-32 by neg sqdist
// (radix select), then q·(PK[idx]-PK[n]) softmax, out = sum attn*(PV[idx]-PV[n])
__global__ __launch_bounds__(256) void knn_attn_kernel(
    const float* __restrict__ feat, const float* __restrict__ sq,
    const float* __restrict__ Qm, const float* __restrict__ PKm, const float* __restrict__ PVm,
    float* __restrict__ t1)
{
  __shared__ float dist[4*Ndim];
  __shared__ __align__(16) float fn[4][64];
  __shared__ __align__(16) float qv[4][64];
  __shared__ __align__(16) float pkn[4][64];
  __shared__ __align__(16) float pvn[4][64];
  __shared__ float en[4][4][32];
  __shared__ unsigned hist[256];
  __shared__ unsigned sS[256];
  __shared__ int outIdx[4][32];
  __shared__ int tieList[64];
  __shared__ unsigned selPrefix, selWant, outCnt, tieCnt;

  const int tid = threadIdx.x;
  const int b = blockIdx.y;
  const int n0 = blockIdx.x*4;
  const float* fb = feat + (size_t)b*Ndim*64;

  { int j = tid>>6, c = tid&63;
    size_t ro = ((size_t)b*Ndim + n0 + j)*64 + c;
    fn[j][c]  = feat[ro];
    qv[j][c]  = Qm[ro];
    pkn[j][c] = PKm[ro];
    pvn[j][c] = PVm[ro];
  }
  const float sqn0 = sq[b*Ndim + n0 + 0];
  const float sqn1 = sq[b*Ndim + n0 + 1];
  const float sqn2 = sq[b*Ndim + n0 + 2];
  const float sqn3 = sq[b*Ndim + n0 + 3];

  // ---- distances: each thread owns 16 m's (4 groups of 4, register-blocked)
  for (int g=0; g<4; ++g){
    float acc[4][4];
    #pragma unroll
    for (int u=0;u<4;++u){ acc[u][0]=0.f; acc[u][1]=0.f; acc[u][2]=0.f; acc[u][3]=0.f; }
    const int mBase = tid + g*1024;
    #pragma unroll 4
    for (int c4=0;c4<16;++c4){
      // query rows: wave-uniform addresses -> scalar loads
      float4 fj0 = *(const float4*)&fb[(size_t)(n0+0)*64 + (c4<<2)];
      float4 fj1 = *(const float4*)&fb[(size_t)(n0+1)*64 + (c4<<2)];
      float4 fj2 = *(const float4*)&fb[(size_t)(n0+2)*64 + (c4<<2)];
      float4 fj3 = *(const float4*)&fb[(size_t)(n0+3)*64 + (c4<<2)];
      #pragma unroll
      for (int u=0;u<4;++u){
        float4 fm = *(const float4*)&fb[(size_t)(mBase + u*256)*64 + (c4<<2)];
        acc[u][0] += dot4(fm, fj0);
        acc[u][1] += dot4(fm, fj1);
        acc[u][2] += dot4(fm, fj2);
        acc[u][3] += dot4(fm, fj3);
      }
    }
    #pragma unroll
    for (int u=0;u<4;++u){
      int m = mBase + u*256;
      float sqm = sq[b*Ndim + m];
      dist[0*Ndim+m] = (2.f*acc[u][0] - sqn0) - sqm;
      dist[1*Ndim+m] = (2.f*acc[u][1] - sqn1) - sqm;
      dist[2*Ndim+m] = (2.f*acc[u][2] - sqn2) - sqm;
      dist[3*Ndim+m] = (2.f*acc[u][3] - sqn3) - sqm;
    }
  }
  __syncthreads();

  // ---- exact top-32 per query row via 4-pass MSB radix select
  for (int j=0;j<4;++j){
    if (tid==0){ selPrefix = 0u; selWant = 32u; }
    __syncthreads();
    for (int shift=24; shift>=0; shift-=8){
      hist[tid] = 0u;
      __syncthreads();
      const unsigned pv = selPrefix;
      const unsigned maskAb = (shift==24) ? 0u : (0xFFFFFFFFu << (shift+8));
      for (int i=0;i<16;++i){
        unsigned u = keyOf(dist[j*Ndim + tid + (i<<8)]);
        if ((u & maskAb) == pv) atomicAdd(&hist[(u>>shift)&255], 1u);
      }
      __syncthreads();
      sS[tid] = hist[tid];
      __syncthreads();
      for (int off=1; off<256; off<<=1){
        unsigned add = (tid+off < 256) ? sS[tid+off] : 0u;
        __syncthreads();
        sS[tid] += add;
        __syncthreads();
      }
      const unsigned want = selWant;
      const unsigned Sb = sS[tid];
      const unsigned Sn = (tid < 255) ? sS[tid+1] : 0u;
      __syncthreads();
      if (Sb >= want && Sn < want){
        selPrefix = pv | ((unsigned)tid << shift);
        selWant   = want - Sn;
      }
      __syncthreads();
    }
    if (tid==0){ outCnt = 0u; tieCnt = 0u; }
    __syncthreads();
    const unsigned T = selPrefix;
    for (int i=0;i<16;++i){
      int m = tid + (i<<8);
      unsigned u = keyOf(dist[j*Ndim + m]);
      if (u > T){
        unsigned p = atomicAdd(&outCnt, 1u);
        if (p < 32u) outIdx[j][p] = m;
      } else if (u == T){
        unsigned p = atomicAdd(&tieCnt, 1u);
        if (p < 64u) tieList[p] = m;
      }
    }
    __syncthreads();
    if (tid==0){
      int r = (int)selWant;
      int base = (int)outCnt;
      int tc = (int)(tieCnt < 64u ? tieCnt : 64u);
      for (int kk=0; kk<r && base+kk<32; ++kk){
        int best = 0x7fffffff, bi = -1;
        for (int t=0;t<tc;++t){ if (tieList[t] < best){ best = tieList[t]; bi = t; } }
        if (bi >= 0){ outIdx[j][base+kk] = best; tieList[bi] = 0x7fffffff; }
      }
    }
    __syncthreads();
  }

  // ---- attention epilogue
  #pragma unroll
  for (int p=0;p<2;++p){
    int task = tid + (p<<8);
    int jn = task>>7, h = (task>>5)&3, kk = task&31;
    int mj = outIdx[jn][kk];
    const float4* pk4 = (const float4*)(PKm + ((size_t)b*Ndim + mj)*64 + h*16);
    const float4* qq4 = (const float4*)&qv[jn][h*16];
    const float4* nn4 = (const float4*)&pkn[jn][h*16];
    float e = 0.f;
    #pragma unroll
    for (int d=0;d<4;++d){
      float4 kv = pk4[d], qq = qq4[d], nn = nn4[d];
      e += qq.x*(kv.x-nn.x) + qq.y*(kv.y-nn.y) + qq.z*(kv.z-nn.z) + qq.w*(kv.w-nn.w);
    }
    en[jn][h][kk] = e * 0.25f;
  }
  __syncthreads();
  if (tid < 16){
    int jn = tid>>2, h = tid&3;
    float mx = -1e30f;
    for (int kk=0;kk<32;++kk) mx = fmaxf(mx, en[jn][h][kk]);
    float ssum = 0.f;
    for (int kk=0;kk<32;++kk){ float ex = expf(en[jn][h][kk]-mx); en[jn][h][kk] = ex; ssum += ex; }
    float inv = 1.f/ssum;
    for (int kk=0;kk<32;++kk) en[jn][h][kk] *= inv;
  }
  __syncthreads();
  {
    int jn = tid>>6, c = tid&63, h = c>>4;
    float acc = 0.f;
    #pragma unroll 8
    for (int kk=0;kk<32;++kk){
      int mj = outIdx[jn][kk];
      acc += en[jn][h][kk] * (PVm[((size_t)b*Ndim + mj)*64 + c] - pvn[jn][c]);
    }
    t1[((size_t)b*Ndim + n0 + jn)*64 + c] = fn[jn][c] + acc;
  }
}

// ---------------------------------------------------------------- BN stats
__global__ __launch_bounds__(256) void bn_stats_kernel(const float* __restrict__ in,
    float* __restrict__ sAcc, float* __restrict__ qAcc)
{
  __shared__ float ps[256], ps2[256];
  const int tid = threadIdx.x;
  const int c = tid&63, rg = tid>>6;
  const size_t base = (size_t)blockIdx.x*128;
  float s = 0.f, s2 = 0.f;
  for (int i=0;i<32;++i){
    float v = in[(base + rg + (size_t)i*4)*64 + c];
    s += v; s2 += v*v;
  }
  ps[tid] = s; ps2[tid] = s2;
  __syncthreads();
  if (tid < 64){
    float S  = ps[tid]+ps[tid+64]+ps[tid+128]+ps[tid+192];
    float S2 = ps2[tid]+ps2[tid+64]+ps2[tid+128]+ps2[tid+192];
    atomicAdd(&sAcc[tid], S);
    atomicAdd(&qAcc[tid], S2);
  }
}

// ---------------------------------------------------------------- MLP
// f1 = BN1(t1); hid = leaky(f1@w1^T); t2 = f1 + hid@w2^T
__global__ __launch_bounds__(256) void mlp_kernel(const float* __restrict__ t1,
    const float* __restrict__ w1, const float* __restrict__ w2,
    const float* __restrict__ g1, const float* __restrict__ b1,
    const float* __restrict__ bns, const float* __restrict__ bnq,
    float* __restrict__ t2)
{
  __shared__ __align__(16) float f1l[64*68];
  __shared__ __align__(16) float hl[64*68];
  __shared__ __align__(16) float w1s[64*64];
  __shared__ __align__(16) float w2s[64*64];
  __shared__ float mu[64], rs[64], gg[64], bb[64];
  const int tid = threadIdx.x;
  if (tid < 64){
    float m = bns[tid] * (1.f/32768.f);
    float v = bnq[tid] * (1.f/32768.f) - m*m;
    mu[tid] = m; rs[tid] = 1.f/sqrtf(v + BN_EPS);
    gg[tid] = g1[tid]; bb[tid] = b1[tid];
  }
  __syncthreads();
  const size_t rowBase = (size_t)blockIdx.x*64;
  for (int k=0;k<16;++k){
    int idx = tid + (k<<8);
    int r = idx>>6, c = idx&63;
    float v = t1[(rowBase + r)*64 + c];
    f1l[r*68+c] = (v - mu[c])*rs[c]*gg[c] + bb[c];
  }
  const int tr = tid>>4, to = tid&15;
  float ff[4][4];
  #pragma unroll
  for (int r=0;r<4;++r){ ff[r][0]=0.f; ff[r][1]=0.f; ff[r][2]=0.f; ff[r][3]=0.f; }

  for (int hc=0; hc<4; ++hc){
    __syncthreads();   // previous chunk consumed / f1l ready
    for (int k=0;k<16;++k){
      int idx = tid + (k<<8);
      int o = idx>>6, c = idx&63;
      w1s[wofs(o, c>>2) + (c&3)] = w1[(size_t)(hc*64+o)*64 + c];
      // w2 chunk: element (cO, oL) from w2[cO*256 + hc*64 + oL]
      w2s[wofs(o /*=cO*/, c>>2) + (c&3)] = w2[(size_t)o*256 + hc*64 + c];
    }
    __syncthreads();
    // hid chunk
    float hv[4][4];
    #pragma unroll
    for (int r=0;r<4;++r){ hv[r][0]=0.f; hv[r][1]=0.f; hv[r][2]=0.f; hv[r][3]=0.f; }
    #pragma unroll 4
    for (int c4=0;c4<16;++c4){
      float4 f[4], w[4];
      #pragma unroll
      for (int r=0;r<4;++r)  f[r] = *(const float4*)&f1l[(4*tr+r)*68 + (c4<<2)];
      #pragma unroll
      for (int oo=0;oo<4;++oo) w[oo] = *(const float4*)&w1s[wofs(4*to+oo, c4)];
      #pragma unroll
      for (int r=0;r<4;++r)
        #pragma unroll
        for (int oo=0;oo<4;++oo)
          hv[r][oo] += dot4(f[r], w[oo]);
    }
    #pragma unroll
    for (int r=0;r<4;++r){
      float4 v;
      float x0=hv[r][0], x1=hv[r][1], x2=hv[r][2], x3=hv[r][3];
      v.x = (x0>0.f)?x0:0.2f*x0; v.y = (x1>0.f)?x1:0.2f*x1;
      v.z = (x2>0.f)?x2:0.2f*x2; v.w = (x3>0.f)?x3:0.2f*x3;
      *(float4*)&hl[(4*tr+r)*68 + 4*to] = v;
    }
    __syncthreads();
    // ff += hid_chunk @ w2_chunk^T
    #pragma unroll 4
    for (int o4=0;o4<16;++o4){
      float4 h[4], w[4];
      #pragma unroll
      for (int r=0;r<4;++r)  h[r] = *(const float4*)&hl[(4*tr+r)*68 + (o4<<2)];
      #pragma unroll
      for (int oo=0;oo<4;++oo) w[oo] = *(const float4*)&w2s[wofs(4*to+oo, o4)];
      #pragma unroll
      for (int r=0;r<4;++r)
        #pragma unroll
        for (int oo=0;oo<4;++oo)
          ff[r][oo] += dot4(h[r], w[oo]);
    }
  }
  #pragma unroll
  for (int r=0;r<4;++r){
    float4 v;
    v.x = f1l[(4*tr+r)*68 + 4*to+0] + ff[r][0];
    v.y = f1l[(4*tr+r)*68 + 4*to+1] + ff[r][1];
    v.z = f1l[(4*tr+r)*68 + 4*to+2] + ff[r][2];
    v.w = f1l[(4*tr+r)*68 + 4*to+3] + ff[r][3];
    *(float4*)&t2[(rowBase + 4*tr + r)*64 + 4*to] = v;
  }
}

// ---------------------------------------------------------------- final BN2 + transpose
__global__ __launch_bounds__(256) void final_kernel(const float* __restrict__ t2,
    const float* __restrict__ bns, const float* __restrict__ bnq,
    const float* __restrict__ g2, const float* __restrict__ b2,
    float* __restrict__ out)
{
  __shared__ float tile[64*65];
  __shared__ float mu[64], rs[64], gg[64], bb[64];
  const int tid = threadIdx.x;
  const int b = blockIdx.y;
  const int n0 = blockIdx.x*64;
  if (tid < 64){
    float m = bns[tid] * (1.f/32768.f);
    float v = bnq[tid] * (1.f/32768.f) - m*m;
    mu[tid] = m; rs[tid] = 1.f/sqrtf(v + BN_EPS);
    gg[tid] = g2[tid]; bb[tid] = b2[tid];
  }
  __syncthreads();
  for (int k=0;k<16;++k){
    int idx = tid + (k<<8);
    int r = idx>>6, c = idx&63;
    float v = t2[((size_t)b*Ndim + n0 + r)*64 + c];
    tile[r*65+c] = (v - mu[c])*rs[c]*gg[c] + bb[c];
  }
  __syncthreads();
  for (int k=0;k<16;++k){
    int idx = tid + (k<<8);
    int c = idx>>6, nn = idx&63;
    out[((size_t)b*64 + c)*Ndim + n0 + nn] = tile[nn*65+c];
  }
}

extern "C" void kernel_launch(void* const* d_in, const int* in_sizes, int n_in,
                              void* d_out, int out_size, void* d_ws, size_t ws_size,
                              hipStream_t stream)
{
  (void)in_sizes; (void)n_in; (void)out_size; (void)ws_size;
  const float* x  = (const float*)d_in[0];
  const float* wq = (const float*)d_in[1];
  const float* wk = (const float*)d_in[2];
  const float* wv = (const float*)d_in[3];
  const float* w1 = (const float*)d_in[4];
  const float* w2 = (const float*)d_in[5];
  const float* g1 = (const float*)d_in[6];
  const float* b1 = (const float*)d_in[7];
  const float* g2 = (const float*)d_in[8];
  const float* b2 = (const float*)d_in[9];
  float* out = (float*)d_out;

  const size_t NE = (size_t)ROWS*64;   // 2097152 elements per (B,N,C) tensor
  float* feat = (float*)d_ws;
  float* sq   = feat + NE;
  float* Qb   = sq + ROWS;
  float* PKb  = Qb + NE;
  float* PVb  = PKb + NE;
  float* t1   = PVb + NE;
  float* t2   = t1 + NE;
  float* acc  = t2 + NE;   // 256 floats: bn1sum, bn1sq, bn2sum, bn2sq

  hipMemsetAsync(acc, 0, 256*sizeof(float), stream);
  prep_kernel<<<dim3(64,8), 256, 0, stream>>>(x, feat, sq);
  proj_kernel<<<dim3(512), 256, 0, stream>>>(feat, wq, wk, wv, Qb, PKb, PVb);
  knn_attn_kernel<<<dim3(1024,8), 256, 0, stream>>>(feat, sq, Qb, PKb, PVb, t1);
  bn_stats_kernel<<<dim3(256), 256, 0, stream>>>(t1, acc, acc+64);
  mlp_kernel<<<dim3(512), 256, 0, stream>>>(t1, w1, w2, g1, b1, acc, acc+64, t2);
  bn_stats_kernel<<<dim3(256), 256, 0, stream>>>(t2, acc+128, acc+192);
  final_kernel<<<dim3(64,8), 256, 0, stream>>>(t2, acc+128, acc+192, g2, b2, out);
}

// Round 4
// 1181.720 us; speedup vs baseline: 1.4229x; 1.4229x over previous
//
#include <hip/hip_runtime.h>

#define Bdim 8
#define Cdim 64
#define Ndim 4096
#define Kdim 32
#define ROWS (Bdim*Ndim)   /* 32768 */
#define BN_EPS 1e-5f

__device__ __forceinline__ float dot4(float4 a, float4 b){
  return a.x*b.x + a.y*b.y + a.z*b.z + a.w*b.w;
}
// XOR-swizzled weight tile layout (see proj/mlp kernels)
__device__ __forceinline__ int wofs(int o, int g){ return o*64 + (((g ^ ((o>>2)&7)))<<2); }
// order-preserving float->uint key (larger float <=> larger key)
__device__ __forceinline__ unsigned keyOf(float f){
  unsigned u = __float_as_uint(f);
  return (u & 0x80000000u) ? ~u : (u ^ 0x80000000u);
}

// ---------------------------------------------------------------- prep
__global__ __launch_bounds__(256) void prep_kernel(const float* __restrict__ x,
    float* __restrict__ feat, float* __restrict__ sq)
{
  __shared__ float tile[64*65];
  const int tid = threadIdx.x;
  const int b = blockIdx.y;
  const int n0 = blockIdx.x*64;
  for (int k=0;k<16;++k){
    int idx = tid + (k<<8);
    int c = idx>>6, nn = idx&63;
    tile[nn*65+c] = x[((size_t)b*64+c)*Ndim + n0 + nn];
  }
  __syncthreads();
  for (int k=0;k<16;++k){
    int idx = tid + (k<<8);
    int r = idx>>6, c = idx&63;
    feat[((size_t)b*Ndim + n0 + r)*64 + c] = tile[r*65+c];
  }
  if (tid < 64){
    float a = 0.f;
    #pragma unroll
    for (int c=0;c<64;++c){ float v = tile[tid*65+c]; a += v*v; }
    sq[b*Ndim + n0 + tid] = a;
  }
}

// ---------------------------------------------------------------- proj
__global__ __launch_bounds__(256) void proj_kernel(const float* __restrict__ feat,
    const float* __restrict__ wq, const float* __restrict__ wk,
    const float* __restrict__ wv,
    float* __restrict__ Qo, float* __restrict__ PKo, float* __restrict__ PVo)
{
  __shared__ __align__(16) float ftile[64*68];
  __shared__ __align__(16) float Ws[3][64*64];
  const int tid = threadIdx.x;
  const size_t rowBase = (size_t)blockIdx.x*64;
  for (int k=0;k<16;++k){
    int idx = tid + (k<<8);
    int r = idx>>6, c = idx&63;
    ftile[r*68+c] = feat[(rowBase + r)*64 + c];
  }
  {
    const float* wp[3] = {wq, wk, wv};
    for (int m=0;m<3;++m)
      for (int k=0;k<16;++k){
        int idx = tid + (k<<8);
        int o = idx>>6, c = idx&63;
        Ws[m][wofs(o, c>>2) + (c&3)] = wp[m][o*64 + c];
      }
  }
  __syncthreads();
  const int tr = tid>>4, to = tid&15;
  float* outp[3] = {Qo, PKo, PVo};
  for (int m=0;m<3;++m){
    float acc[4][4];
    #pragma unroll
    for (int r=0;r<4;++r){ acc[r][0]=0.f; acc[r][1]=0.f; acc[r][2]=0.f; acc[r][3]=0.f; }
    #pragma unroll 4
    for (int c4=0;c4<16;++c4){
      float4 f[4], w[4];
      #pragma unroll
      for (int r=0;r<4;++r)  f[r] = *(const float4*)&ftile[(4*tr+r)*68 + (c4<<2)];
      #pragma unroll
      for (int oo=0;oo<4;++oo) w[oo] = *(const float4*)&Ws[m][wofs(4*to+oo, c4)];
      #pragma unroll
      for (int r=0;r<4;++r)
        #pragma unroll
        for (int oo=0;oo<4;++oo)
          acc[r][oo] += dot4(f[r], w[oo]);
    }
    #pragma unroll
    for (int r=0;r<4;++r){
      float4 v; v.x=acc[r][0]; v.y=acc[r][1]; v.z=acc[r][2]; v.w=acc[r][3];
      *(float4*)&outp[m][(rowBase + 4*tr + r)*64 + 4*to] = v;
    }
  }
}

// ---------------------------------------------------------------- knn + attention
// 512 threads, 4 query rows/WG. Coalesced x-based distances. Per-wave exact
// top-32 radix select using register-only cross-lane comm (ballot/shfl);
// outIdx pre-filled with valid indices so a wild global read is impossible.
__global__ __launch_bounds__(512) void knn_attn_kernel(
    const float* __restrict__ x,
    const float* __restrict__ feat, const float* __restrict__ sq,
    const float* __restrict__ Qm, const float* __restrict__ PKm, const float* __restrict__ PVm,
    float* __restrict__ t1)
{
  __shared__ float dist[4*Ndim];                 // 64 KB
  __shared__ __align__(16) float fn[4][64];
  __shared__ __align__(16) float qv[4][64];
  __shared__ __align__(16) float pkn[4][64];
  __shared__ __align__(16) float pvn[4][64];
  __shared__ float en[4][4][32];
  __shared__ __align__(16) unsigned hist[4][256];
  __shared__ int outIdx[4][32];
  __shared__ int tieL[4][64];

  const int tid = threadIdx.x;
  const int blk = blockIdx.x;
  const int b  = blk & 7;
  const int n0 = (blk >> 3) * 4;
  const float* xb = x + (size_t)b*64*Ndim;

  if (tid < 256){
    int j = tid>>6, c = tid&63;
    size_t ro = ((size_t)b*Ndim + n0 + j)*64 + c;
    fn[j][c]  = feat[ro];
    qv[j][c]  = Qm[ro];
    pkn[j][c] = PKm[ro];
    pvn[j][c] = PVm[ro];
  }
  const float sqn0 = sq[b*Ndim + n0 + 0];
  const float sqn1 = sq[b*Ndim + n0 + 1];
  const float sqn2 = sq[b*Ndim + n0 + 2];
  const float sqn3 = sq[b*Ndim + n0 + 3];

  // ---- distances: coalesced float4 m-loads from x (B,C,N)
  #pragma unroll
  for (int g=0; g<2; ++g){
    const int m0 = g*2048 + tid*4;
    float acc[4][4];   // [query][m-lane]
    #pragma unroll
    for (int j=0;j<4;++j){ acc[j][0]=0.f; acc[j][1]=0.f; acc[j][2]=0.f; acc[j][3]=0.f; }
    #pragma unroll 4
    for (int c=0;c<64;++c){
      float4 qq = *(const float4*)&xb[(size_t)c*Ndim + n0];   // wave-uniform (4 queries)
      float4 xm = *(const float4*)&xb[(size_t)c*Ndim + m0];   // coalesced
      acc[0][0] += qq.x*xm.x; acc[0][1] += qq.x*xm.y; acc[0][2] += qq.x*xm.z; acc[0][3] += qq.x*xm.w;
      acc[1][0] += qq.y*xm.x; acc[1][1] += qq.y*xm.y; acc[1][2] += qq.y*xm.z; acc[1][3] += qq.y*xm.w;
      acc[2][0] += qq.z*xm.x; acc[2][1] += qq.z*xm.y; acc[2][2] += qq.z*xm.z; acc[2][3] += qq.z*xm.w;
      acc[3][0] += qq.w*xm.x; acc[3][1] += qq.w*xm.y; acc[3][2] += qq.w*xm.z; acc[3][3] += qq.w*xm.w;
    }
    float4 sqm = *(const float4*)&sq[b*Ndim + m0];
    const float sqn[4] = {sqn0, sqn1, sqn2, sqn3};
    #pragma unroll
    for (int j=0;j<4;++j){
      float4 v;
      v.x = (2.f*acc[j][0] - sqn[j]) - sqm.x;
      v.y = (2.f*acc[j][1] - sqn[j]) - sqm.y;
      v.z = (2.f*acc[j][2] - sqn[j]) - sqm.z;
      v.w = (2.f*acc[j][3] - sqn[j]) - sqm.w;
      *(float4*)&dist[j*Ndim + m0] = v;
    }
  }
  __syncthreads();

  // ---- exact top-32 per query, one wave per query (waves 0-3)
  const int lane = tid & 63;
  const int w = tid >> 6;
  if (w < 4){
    // defensive pre-fill: any slot selection fails to write stays a VALID index
    if (lane < 32) outIdx[w][lane] = n0 + w;
    tieL[w][lane] = n0 + w;

    const float* dj = dist + w*Ndim;
    unsigned prefix = 0u, want = 32u;
    #pragma unroll
    for (int shift=24; shift>=0; shift-=8){
      #pragma unroll
      for (int i=0;i<4;++i) hist[w][lane + (i<<6)] = 0u;
      __threadfence_block();
      const unsigned maskAb = (shift==24) ? 0u : (0xFFFFFFFFu << (shift+8));
      for (int i=0;i<64;++i){
        unsigned u = keyOf(dj[lane + (i<<6)]);
        if ((u & maskAb) == prefix) atomicAdd(&hist[w][(u>>shift)&255], 1u);
      }
      __threadfence_block();
      uint4 cc = *(const uint4*)&hist[w][4*lane];
      unsigned sum4 = cc.x + cc.y + cc.z + cc.w;
      unsigned s = sum4;                 // inclusive suffix scan over lanes
      #pragma unroll
      for (int off=1; off<64; off<<=1){
        unsigned t = (unsigned)__shfl_down((int)s, off, 64);
        if (lane + off < 64) s += t;
      }
      unsigned S0 = s, S1 = s - cc.x, S2 = S1 - cc.y, S3 = S2 - cc.z, S4 = s - sum4;
      unsigned val = 0u;                 // pack (bin<<16)|newWant on the unique lane
      if (S0 >= want && S1 < want) val = ((unsigned)(4*lane+0) << 16) | (want - S1);
      if (S1 >= want && S2 < want) val = ((unsigned)(4*lane+1) << 16) | (want - S2);
      if (S2 >= want && S3 < want) val = ((unsigned)(4*lane+2) << 16) | (want - S3);
      if (S3 >= want && S4 < want) val = ((unsigned)(4*lane+3) << 16) | (want - S4);
      #pragma unroll
      for (int off=32; off>=1; off>>=1) val |= (unsigned)__shfl_xor((int)val, off, 64);
      unsigned bin = val >> 16; want = val & 0xFFFFu;
      if (val == 0u){ bin = 255u; want = 1u; }   // unreachable fallback, keeps bounded
      prefix |= bin << shift;
    }
    // gather via ballot compaction (deterministic, ascending-m order)
    const unsigned T = prefix;
    int base = 0, tbase = 0;
    for (int i=0;i<64;++i){
      int m = lane + (i<<6);
      unsigned u = keyOf(dj[m]);
      unsigned long long mg = __ballot(u > T);
      unsigned long long mt = __ballot(u == T);
      unsigned long long below = (1ull << lane) - 1ull;
      if (u > T){
        int slot = base + (int)__popcll(mg & below);
        if (slot < 32) outIdx[w][slot] = m;
      } else if (u == T){
        int slot = tbase + (int)__popcll(mt & below);
        if (slot < 64) tieL[w][slot] = m;
      }
      base  += (int)__popcll(mg);
      tbase += (int)__popcll(mt);
    }
    __threadfence_block();
    int need = 32 - base;                 // fill remaining slots with smallest-index ties
    if (need > 0 && lane < need){
      int slot = base + lane;
      if (slot >= 0 && slot < 32) outIdx[w][slot] = tieL[w][lane];
    }
  }
  __syncthreads();

  // ---- attention energies: 512 tasks = 4q x 4h x 32k
  {
    int jn = tid>>7, h = (tid>>5)&3, kk = tid&31;
    int mj = outIdx[jn][kk] & (Ndim-1);
    const float4* pk4 = (const float4*)(PKm + ((size_t)b*Ndim + mj)*64 + h*16);
    const float4* qq4 = (const float4*)&qv[jn][h*16];
    const float4* nn4 = (const float4*)&pkn[jn][h*16];
    float e = 0.f;
    #pragma unroll
    for (int d=0;d<4;++d){
      float4 kv = pk4[d], qq = qq4[d], nn = nn4[d];
      e += qq.x*(kv.x-nn.x) + qq.y*(kv.y-nn.y) + qq.z*(kv.z-nn.z) + qq.w*(kv.w-nn.w);
    }
    en[jn][h][kk] = e * 0.25f;
  }
  __syncthreads();
  if (tid < 16){
    int jn = tid>>2, h = tid&3;
    float mx = -1e30f;
    for (int kk=0;kk<32;++kk) mx = fmaxf(mx, en[jn][h][kk]);
    float ssum = 0.f;
    for (int kk=0;kk<32;++kk){ float ex = expf(en[jn][h][kk]-mx); en[jn][h][kk] = ex; ssum += ex; }
    float inv = 1.f/ssum;
    for (int kk=0;kk<32;++kk) en[jn][h][kk] *= inv;
  }
  __syncthreads();
  if (tid < 256){
    int jn = tid>>6, c = tid&63, h = c>>4;
    float acc = 0.f;
    #pragma unroll 8
    for (int kk=0;kk<32;++kk){
      int mj = outIdx[jn][kk] & (Ndim-1);
      acc += en[jn][h][kk] * (PVm[((size_t)b*Ndim + mj)*64 + c] - pvn[jn][c]);
    }
    t1[((size_t)b*Ndim + n0 + jn)*64 + c] = fn[jn][c] + acc;
  }
}

// ---------------------------------------------------------------- BN stats
__global__ __launch_bounds__(256) void bn_stats_kernel(const float* __restrict__ in,
    float* __restrict__ sAcc, float* __restrict__ qAcc)
{
  __shared__ float ps[256], ps2[256];
  const int tid = threadIdx.x;
  const int c = tid&63, rg = tid>>6;
  const size_t base = (size_t)blockIdx.x*128;
  float s = 0.f, s2 = 0.f;
  for (int i=0;i<32;++i){
    float v = in[(base + rg + (size_t)i*4)*64 + c];
    s += v; s2 += v*v;
  }
  ps[tid] = s; ps2[tid] = s2;
  __syncthreads();
  if (tid < 64){
    float S  = ps[tid]+ps[tid+64]+ps[tid+128]+ps[tid+192];
    float S2 = ps2[tid]+ps2[tid+64]+ps2[tid+128]+ps2[tid+192];
    atomicAdd(&sAcc[tid], S);
    atomicAdd(&qAcc[tid], S2);
  }
}

// ---------------------------------------------------------------- MLP
__global__ __launch_bounds__(256) void mlp_kernel(const float* __restrict__ t1,
    const float* __restrict__ w1, const float* __restrict__ w2,
    const float* __restrict__ g1, const float* __restrict__ b1,
    const float* __restrict__ bns, const float* __restrict__ bnq,
    float* __restrict__ t2)
{
  __shared__ __align__(16) float f1l[64*68];
  __shared__ __align__(16) float hl[64*68];
  __shared__ __align__(16) float w1s[64*64];
  __shared__ __align__(16) float w2s[64*64];
  __shared__ float mu[64], rs[64], gg[64], bb[64];
  const int tid = threadIdx.x;
  if (tid < 64){
    float m = bns[tid] * (1.f/32768.f);
    float v = bnq[tid] * (1.f/32768.f) - m*m;
    mu[tid] = m; rs[tid] = 1.f/sqrtf(v + BN_EPS);
    gg[tid] = g1[tid]; bb[tid] = b1[tid];
  }
  __syncthreads();
  const size_t rowBase = (size_t)blockIdx.x*64;
  for (int k=0;k<16;++k){
    int idx = tid + (k<<8);
    int r = idx>>6, c = idx&63;
    float v = t1[(rowBase + r)*64 + c];
    f1l[r*68+c] = (v - mu[c])*rs[c]*gg[c] + bb[c];
  }
  const int tr = tid>>4, to = tid&15;
  float ff[4][4];
  #pragma unroll
  for (int r=0;r<4;++r){ ff[r][0]=0.f; ff[r][1]=0.f; ff[r][2]=0.f; ff[r][3]=0.f; }

  for (int hc=0; hc<4; ++hc){
    __syncthreads();
    for (int k=0;k<16;++k){
      int idx = tid + (k<<8);
      int o = idx>>6, c = idx&63;
      w1s[wofs(o, c>>2) + (c&3)] = w1[(size_t)(hc*64+o)*64 + c];
      w2s[wofs(o, c>>2) + (c&3)] = w2[(size_t)o*256 + hc*64 + c];
    }
    __syncthreads();
    float hv[4][4];
    #pragma unroll
    for (int r=0;r<4;++r){ hv[r][0]=0.f; hv[r][1]=0.f; hv[r][2]=0.f; hv[r][3]=0.f; }
    #pragma unroll 4
    for (int c4=0;c4<16;++c4){
      float4 f[4], w[4];
      #pragma unroll
      for (int r=0;r<4;++r)  f[r] = *(const float4*)&f1l[(4*tr+r)*68 + (c4<<2)];
      #pragma unroll
      for (int oo=0;oo<4;++oo) w[oo] = *(const float4*)&w1s[wofs(4*to+oo, c4)];
      #pragma unroll
      for (int r=0;r<4;++r)
        #pragma unroll
        for (int oo=0;oo<4;++oo)
          hv[r][oo] += dot4(f[r], w[oo]);
    }
    #pragma unroll
    for (int r=0;r<4;++r){
      float4 v;
      float x0=hv[r][0], x1=hv[r][1], x2=hv[r][2], x3=hv[r][3];
      v.x = (x0>0.f)?x0:0.2f*x0; v.y = (x1>0.f)?x1:0.2f*x1;
      v.z = (x2>0.f)?x2:0.2f*x2; v.w = (x3>0.f)?x3:0.2f*x3;
      *(float4*)&hl[(4*tr+r)*68 + 4*to] = v;
    }
    __syncthreads();
    #pragma unroll 4
    for (int o4=0;o4<16;++o4){
      float4 h[4], w[4];
      #pragma unroll
      for (int r=0;r<4;++r)  h[r] = *(const float4*)&hl[(4*tr+r)*68 + (o4<<2)];
      #pragma unroll
      for (int oo=0;oo<4;++oo) w[oo] = *(const float4*)&w2s[wofs(4*to+oo, o4)];
      #pragma unroll
      for (int r=0;r<4;++r)
        #pragma unroll
        for (int oo=0;oo<4;++oo)
          ff[r][oo] += dot4(h[r], w[oo]);
    }
  }
  #pragma unroll
  for (int r=0;r<4;++r){
    float4 v;
    v.x = f1l[(4*tr+r)*68 + 4*to+0] + ff[r][0];
    v.y = f1l[(4*tr+r)*68 + 4*to+1] + ff[r][1];
    v.z = f1l[(4*tr+r)*68 + 4*to+2] + ff[r][2];
    v.w = f1l[(4*tr+r)*68 + 4*to+3] + ff[r][3];
    *(float4*)&t2[(rowBase + 4*tr + r)*64 + 4*to] = v;
  }
}

// ---------------------------------------------------------------- final BN2 + transpose
__global__ __launch_bounds__(256) void final_kernel(const float* __restrict__ t2,
    const float* __restrict__ bns, const float* __restrict__ bnq,
    const float* __restrict__ g2, const float* __restrict__ b2,
    float* __restrict__ out)
{
  __shared__ float tile[64*65];
  __shared__ float mu[64], rs[64], gg[64], bb[64];
  const int tid = threadIdx.x;
  const int b = blockIdx.y;
  const int n0 = blockIdx.x*64;
  if (tid < 64){
    float m = bns[tid] * (1.f/32768.f);
    float v = bnq[tid] * (1.f/32768.f) - m*m;
    mu[tid] = m; rs[tid] = 1.f/sqrtf(v + BN_EPS);
    gg[tid] = g2[tid]; bb[tid] = b2[tid];
  }
  __syncthreads();
  for (int k=0;k<16;++k){
    int idx = tid + (k<<8);
    int r = idx>>6, c = idx&63;
    float v = t2[((size_t)b*Ndim + n0 + r)*64 + c];
    tile[r*65+c] = (v - mu[c])*rs[c]*gg[c] + bb[c];
  }
  __syncthreads();
  for (int k=0;k<16;++k){
    int idx = tid + (k<<8);
    int c = idx>>6, nn = idx&63;
    out[((size_t)b*64 + c)*Ndim + n0 + nn] = tile[nn*65+c];
  }
}

extern "C" void kernel_launch(void* const* d_in, const int* in_sizes, int n_in,
                              void* d_out, int out_size, void* d_ws, size_t ws_size,
                              hipStream_t stream)
{
  (void)in_sizes; (void)n_in; (void)out_size; (void)ws_size;
  const float* x  = (const float*)d_in[0];
  const float* wq = (const float*)d_in[1];
  const float* wk = (const float*)d_in[2];
  const float* wv = (const float*)d_in[3];
  const float* w1 = (const float*)d_in[4];
  const float* w2 = (const float*)d_in[5];
  const float* g1 = (const float*)d_in[6];
  const float* b1 = (const float*)d_in[7];
  const float* g2 = (const float*)d_in[8];
  const float* b2 = (const float*)d_in[9];
  float* out = (float*)d_out;

  const size_t NE = (size_t)ROWS*64;
  float* feat = (float*)d_ws;
  float* sq   = feat + NE;
  float* Qb   = sq + ROWS;
  float* PKb  = Qb + NE;
  float* PVb  = PKb + NE;
  float* t1   = PVb + NE;
  float* t2   = t1 + NE;
  float* acc  = t2 + NE;   // 256 floats: bn1sum, bn1sq, bn2sum, bn2sq

  hipMemsetAsync(acc, 0, 256*sizeof(float), stream);
  prep_kernel<<<dim3(64,8), 256, 0, stream>>>(x, feat, sq);
  proj_kernel<<<dim3(512), 256, 0, stream>>>(feat, wq, wk, wv, Qb, PKb, PVb);
  knn_attn_kernel<<<dim3(8192), 512, 0, stream>>>(x, feat, sq, Qb, PKb, PVb, t1);
  bn_stats_kernel<<<dim3(256), 256, 0, stream>>>(t1, acc, acc+64);
  mlp_kernel<<<dim3(512), 256, 0, stream>>>(t1, w1, w2, g1, b1, acc, acc+64, t2);
  bn_stats_kernel<<<dim3(256), 256, 0, stream>>>(t2, acc+128, acc+192);
  final_kernel<<<dim3(64,8), 256, 0, stream>>>(t2, acc+128, acc+192, g2, b2, out);
}

// Round 5
// 873.762 us; speedup vs baseline: 1.9244x; 1.3525x over previous
//
#include <hip/hip_runtime.h>

#define Bdim 8
#define Cdim 64
#define Ndim 4096
#define Kdim 32
#define ROWS (Bdim*Ndim)   /* 32768 */
#define BN_EPS 1e-5f

__device__ __forceinline__ float dot4(float4 a, float4 b){
  return a.x*b.x + a.y*b.y + a.z*b.z + a.w*b.w;
}
__device__ __forceinline__ int wofs(int o, int g){ return o*64 + (((g ^ ((o>>2)&7)))<<2); }
__device__ __forceinline__ unsigned keyOf(float f){
  unsigned u = __float_as_uint(f);
  return (u & 0x80000000u) ? ~u : (u ^ 0x80000000u);
}

// ---------------------------------------------------------------- prep
__global__ __launch_bounds__(256) void prep_kernel(const float* __restrict__ x,
    float* __restrict__ feat, float* __restrict__ sq)
{
  __shared__ float tile[64*65];
  const int tid = threadIdx.x;
  const int b = blockIdx.y;
  const int n0 = blockIdx.x*64;
  for (int k=0;k<16;++k){
    int idx = tid + (k<<8);
    int c = idx>>6, nn = idx&63;
    tile[nn*65+c] = x[((size_t)b*64+c)*Ndim + n0 + nn];
  }
  __syncthreads();
  for (int k=0;k<16;++k){
    int idx = tid + (k<<8);
    int r = idx>>6, c = idx&63;
    feat[((size_t)b*Ndim + n0 + r)*64 + c] = tile[r*65+c];
  }
  if (tid < 64){
    float a = 0.f;
    #pragma unroll
    for (int c=0;c<64;++c){ float v = tile[tid*65+c]; a += v*v; }
    sq[b*Ndim + n0 + tid] = a;
  }
}

// ---------------------------------------------------------------- proj
__global__ __launch_bounds__(256) void proj_kernel(const float* __restrict__ feat,
    const float* __restrict__ wq, const float* __restrict__ wk,
    const float* __restrict__ wv,
    float* __restrict__ Qo, float* __restrict__ PKo, float* __restrict__ PVo)
{
  __shared__ __align__(16) float ftile[64*68];
  __shared__ __align__(16) float Ws[3][64*64];
  const int tid = threadIdx.x;
  const size_t rowBase = (size_t)blockIdx.x*64;
  for (int k=0;k<16;++k){
    int idx = tid + (k<<8);
    int r = idx>>6, c = idx&63;
    ftile[r*68+c] = feat[(rowBase + r)*64 + c];
  }
  {
    const float* wp[3] = {wq, wk, wv};
    for (int m=0;m<3;++m)
      for (int k=0;k<16;++k){
        int idx = tid + (k<<8);
        int o = idx>>6, c = idx&63;
        Ws[m][wofs(o, c>>2) + (c&3)] = wp[m][o*64 + c];
      }
  }
  __syncthreads();
  const int tr = tid>>4, to = tid&15;
  float* outp[3] = {Qo, PKo, PVo};
  for (int m=0;m<3;++m){
    float acc[4][4];
    #pragma unroll
    for (int r=0;r<4;++r){ acc[r][0]=0.f; acc[r][1]=0.f; acc[r][2]=0.f; acc[r][3]=0.f; }
    #pragma unroll 4
    for (int c4=0;c4<16;++c4){
      float4 f[4], w[4];
      #pragma unroll
      for (int r=0;r<4;++r)  f[r] = *(const float4*)&ftile[(4*tr+r)*68 + (c4<<2)];
      #pragma unroll
      for (int oo=0;oo<4;++oo) w[oo] = *(const float4*)&Ws[m][wofs(4*to+oo, c4)];
      #pragma unroll
      for (int r=0;r<4;++r)
        #pragma unroll
        for (int oo=0;oo<4;++oo)
          acc[r][oo] += dot4(f[r], w[oo]);
    }
    #pragma unroll
    for (int r=0;r<4;++r){
      float4 v; v.x=acc[r][0]; v.y=acc[r][1]; v.z=acc[r][2]; v.w=acc[r][3];
      *(float4*)&outp[m][(rowBase + 4*tr + r)*64 + 4*to] = v;
    }
  }
}

// ---------------------------------------------------------------- knn + attention
// 512 threads, 8 queries/WG. Coalesced x-based distances -> 32KB LDS chunk
// (4 queries at a time) -> 64 register keys per lane; wave j selects query j
// (all 8 waves). Selection arrays alias the dead chunk region.
__global__ __launch_bounds__(512, 4) void knn_attn_kernel(
    const float* __restrict__ x,
    const float* __restrict__ feat, const float* __restrict__ sq,
    const float* __restrict__ Qm, const float* __restrict__ PKm, const float* __restrict__ PVm,
    float* __restrict__ t1)
{
  __shared__ __align__(16) unsigned char smem[43040];
  float*    chunkF = (float*)smem;                 // [4][2048]  (32 KB, reused)
  unsigned* histU  = (unsigned*)smem;              // [8][256]   (alias, selection)
  int*      outIdx = (int*)(smem + 8192);          // [8][32]
  int*      tieL   = (int*)(smem + 9216);          // [8][64]
  float*    enS    = (float*)(smem + 11264);       // [8][4][32]
  float*    fnS    = (float*)(smem + 32768);       // [8][64]
  float*    qvS    = (float*)(smem + 34816);       // [8][64]
  float*    pknS   = (float*)(smem + 36864);       // [8][64]
  float*    pvnS   = (float*)(smem + 38912);       // [8][64]
  float*    qT     = (float*)(smem + 40960);       // [64][8] query x-values
  float*    sqnS   = (float*)(smem + 43008);       // [8]

  const int tid = threadIdx.x;
  const int lane = tid & 63;
  const int w = tid >> 6;
  const int blk = blockIdx.x;
  const int b  = blk & 7;                          // XCD-locality swizzle
  const int n0 = (blk >> 3) << 3;                  // 8 queries
  const float* xb = x + (size_t)b*64*Ndim;

  {
    int j = tid>>6, c = tid&63;
    size_t ro = ((size_t)b*Ndim + n0 + j)*64 + c;
    fnS[tid]  = feat[ro];
    qvS[tid]  = Qm[ro];
    pknS[tid] = PKm[ro];
    pvnS[tid] = PVm[ro];
    int cc = tid>>3, q2 = tid&7;
    qT[tid] = xb[(size_t)cc*Ndim + n0 + q2];
    if (tid < 8) sqnS[tid] = sq[b*Ndim + n0 + tid];
  }
  __syncthreads();

  unsigned kk[64];

  #pragma unroll
  for (int g=0; g<2; ++g){
    const int m0 = (g<<11) + (tid<<2);
    float acc[8][4];
    #pragma unroll
    for (int q=0;q<8;++q){ acc[q][0]=0.f; acc[q][1]=0.f; acc[q][2]=0.f; acc[q][3]=0.f; }
    #pragma unroll 4
    for (int c=0;c<64;++c){
      float4 xm = *(const float4*)&xb[(size_t)c*Ndim + m0];   // coalesced
      float4 qA = *(const float4*)&qT[(c<<3)];                 // LDS broadcast
      float4 qB = *(const float4*)&qT[(c<<3)+4];
      const float qs[8] = {qA.x,qA.y,qA.z,qA.w,qB.x,qB.y,qB.z,qB.w};
      #pragma unroll
      for (int q=0;q<8;++q){
        acc[q][0] += qs[q]*xm.x; acc[q][1] += qs[q]*xm.y;
        acc[q][2] += qs[q]*xm.z; acc[q][3] += qs[q]*xm.w;
      }
    }
    float4 sqm4 = *(const float4*)&sq[b*Ndim + m0];
    #pragma unroll
    for (int half=0; half<2; ++half){
      __syncthreads();   // chunk free (or consumed by previous half)
      #pragma unroll
      for (int qq=0;qq<4;++qq){
        int q = (half<<2)+qq;
        float sqn_q = sqnS[q];
        float4 v;
        v.x = (2.f*acc[q][0]-sqn_q)-sqm4.x;
        v.y = (2.f*acc[q][1]-sqn_q)-sqm4.y;
        v.z = (2.f*acc[q][2]-sqn_q)-sqm4.z;
        v.w = (2.f*acc[q][3]-sqn_q)-sqm4.w;
        *(float4*)&chunkF[(qq<<11) + (tid<<2)] = v;
      }
      __syncthreads();
      if ((w>>2) == half){
        const int wq = w & 3;
        #pragma unroll
        for (int i=0;i<32;++i)
          kk[(g<<5)+i] = keyOf(chunkF[(wq<<11)+(i<<6)+lane]);
      }
    }
  }
  __syncthreads();   // chunk dead -> selection arrays may alias it

  // defensive pre-fill: unwritten slots stay VALID indices
  if (lane < 32) outIdx[(w<<5)+lane] = n0 + w;
  tieL[(w<<6)+lane] = n0 + w;

  // ---- exact top-32, wave w handles query w, keys in registers
  unsigned prefix = 0u, want = 32u;
  #pragma unroll
  for (int pass=0; pass<4; ++pass){
    const int shift = 24-(pass<<3);
    histU[(w<<8)+lane] = 0u; histU[(w<<8)+64+lane] = 0u;
    histU[(w<<8)+128+lane] = 0u; histU[(w<<8)+192+lane] = 0u;
    __threadfence_block();
    const unsigned maskAb = (pass==0) ? 0u : (0xFFFFFFFFu << (32-(pass<<3)));
    #pragma unroll
    for (int i=0;i<64;++i){
      unsigned u = kk[i];
      if ((u & maskAb) == prefix) atomicAdd(&histU[(w<<8)+((u>>shift)&255u)], 1u);
    }
    __threadfence_block();
    uint4 cc = *(const uint4*)&histU[(w<<8)+(lane<<2)];
    unsigned sum4 = cc.x+cc.y+cc.z+cc.w;
    unsigned s = sum4;
    #pragma unroll
    for (int off=1; off<64; off<<=1){
      unsigned t = (unsigned)__shfl_down((int)s, off, 64);
      if (lane + off < 64) s += t;
    }
    unsigned S0=s, S1=s-cc.x, S2=S1-cc.y, S3=S2-cc.z, S4=s-sum4;
    unsigned val = 0u;
    if (S0 >= want && S1 < want) val = ((unsigned)((lane<<2)+0) << 16) | (want - S1);
    if (S1 >= want && S2 < want) val = ((unsigned)((lane<<2)+1) << 16) | (want - S2);
    if (S2 >= want && S3 < want) val = ((unsigned)((lane<<2)+2) << 16) | (want - S3);
    if (S3 >= want && S4 < want) val = ((unsigned)((lane<<2)+3) << 16) | (want - S4);
    #pragma unroll
    for (int off=32; off>=1; off>>=1) val |= (unsigned)__shfl_xor((int)val, off, 64);
    unsigned bin = val >> 16; want = val & 0xFFFFu;
    if (val == 0u){ bin = 255u; want = 1u; }   // unreachable fallback, keeps bounded
    prefix |= bin << shift;
  }
  // gather via ballot compaction (ascending-m, lowest-index tie rule)
  {
    const unsigned T = prefix;
    int base = 0, tbase = 0;
    #pragma unroll
    for (int i=0;i<64;++i){
      const int m = ((i>>5)<<11) + ((i&31)<<6) + lane;
      unsigned u = kk[i];
      unsigned long long mg = __ballot(u > T);
      unsigned long long mt = __ballot(u == T);
      unsigned long long below = (1ull << lane) - 1ull;
      if (u > T){
        int slot = base + (int)__popcll(mg & below);
        if (slot < 32) outIdx[(w<<5)+slot] = m;
      } else if (u == T){
        int slot = tbase + (int)__popcll(mt & below);
        if (slot < 64) tieL[(w<<6)+slot] = m;
      }
      base  += (int)__popcll(mg);
      tbase += (int)__popcll(mt);
    }
    __threadfence_block();
    int need = 32 - base;
    if (need > 0 && lane < need){
      int slot = base + lane;
      if (slot >= 0 && slot < 32) outIdx[(w<<5)+slot] = tieL[(w<<6)+lane];
    }
  }
  __syncthreads();

  // ---- attention energies: 1024 tasks = 8q x 4h x 32k
  #pragma unroll
  for (int p=0;p<2;++p){
    int task = tid + (p<<9);
    int jn = task>>7, h = (task>>5)&3, k2 = task&31;
    int mj = outIdx[(jn<<5)+k2] & (Ndim-1);
    const float4* pk4 = (const float4*)(PKm + ((size_t)b*Ndim + mj)*64 + (h<<4));
    const float4* qq4 = (const float4*)&qvS[(jn<<6)+(h<<4)];
    const float4* nn4 = (const float4*)&pknS[(jn<<6)+(h<<4)];
    float e = 0.f;
    #pragma unroll
    for (int d=0;d<4;++d){
      float4 kv = pk4[d], qq = qq4[d], nn = nn4[d];
      e += qq.x*(kv.x-nn.x) + qq.y*(kv.y-nn.y) + qq.z*(kv.z-nn.z) + qq.w*(kv.w-nn.w);
    }
    enS[(jn<<7)+(h<<5)+k2] = e * 0.25f;
  }
  __syncthreads();
  if (tid < 32){
    int jn = tid>>2, h = tid&3;
    float* ep = &enS[(jn<<7)+(h<<5)];
    float mx = -1e30f;
    for (int k2=0;k2<32;++k2) mx = fmaxf(mx, ep[k2]);
    float ssum = 0.f;
    for (int k2=0;k2<32;++k2){ float ex = expf(ep[k2]-mx); ep[k2] = ex; ssum += ex; }
    float inv = 1.f/ssum;
    for (int k2=0;k2<32;++k2) ep[k2] *= inv;
  }
  __syncthreads();
  {
    int jn = tid>>6, c = tid&63, h = c>>4;
    float a2 = 0.f;
    #pragma unroll 8
    for (int k2=0;k2<32;++k2){
      int mj = outIdx[(jn<<5)+k2] & (Ndim-1);
      a2 += enS[(jn<<7)+(h<<5)+k2] * (PVm[((size_t)b*Ndim + mj)*64 + c] - pvnS[(jn<<6)+c]);
    }
    t1[((size_t)b*Ndim + n0 + jn)*64 + c] = fnS[(jn<<6)+c] + a2;
  }
}

// ---------------------------------------------------------------- BN stats
__global__ __launch_bounds__(256) void bn_stats_kernel(const float* __restrict__ in,
    float* __restrict__ sAcc, float* __restrict__ qAcc)
{
  __shared__ float ps[256], ps2[256];
  const int tid = threadIdx.x;
  const int c = tid&63, rg = tid>>6;
  const size_t base = (size_t)blockIdx.x*128;
  float s = 0.f, s2 = 0.f;
  for (int i=0;i<32;++i){
    float v = in[(base + rg + (size_t)i*4)*64 + c];
    s += v; s2 += v*v;
  }
  ps[tid] = s; ps2[tid] = s2;
  __syncthreads();
  if (tid < 64){
    float S  = ps[tid]+ps[tid+64]+ps[tid+128]+ps[tid+192];
    float S2 = ps2[tid]+ps2[tid+64]+ps2[tid+128]+ps2[tid+192];
    atomicAdd(&sAcc[tid], S);
    atomicAdd(&qAcc[tid], S2);
  }
}

// ---------------------------------------------------------------- MLP
__global__ __launch_bounds__(256) void mlp_kernel(const float* __restrict__ t1,
    const float* __restrict__ w1, const float* __restrict__ w2,
    const float* __restrict__ g1, const float* __restrict__ b1,
    const float* __restrict__ bns, const float* __restrict__ bnq,
    float* __restrict__ t2)
{
  __shared__ __align__(16) float f1l[64*68];
  __shared__ __align__(16) float hl[64*68];
  __shared__ __align__(16) float w1s[64*64];
  __shared__ __align__(16) float w2s[64*64];
  __shared__ float mu[64], rs[64], gg[64], bb[64];
  const int tid = threadIdx.x;
  if (tid < 64){
    float m = bns[tid] * (1.f/32768.f);
    float v = bnq[tid] * (1.f/32768.f) - m*m;
    mu[tid] = m; rs[tid] = 1.f/sqrtf(v + BN_EPS);
    gg[tid] = g1[tid]; bb[tid] = b1[tid];
  }
  __syncthreads();
  const size_t rowBase = (size_t)blockIdx.x*64;
  for (int k=0;k<16;++k){
    int idx = tid + (k<<8);
    int r = idx>>6, c = idx&63;
    float v = t1[(rowBase + r)*64 + c];
    f1l[r*68+c] = (v - mu[c])*rs[c]*gg[c] + bb[c];
  }
  const int tr = tid>>4, to = tid&15;
  float ff[4][4];
  #pragma unroll
  for (int r=0;r<4;++r){ ff[r][0]=0.f; ff[r][1]=0.f; ff[r][2]=0.f; ff[r][3]=0.f; }

  for (int hc=0; hc<4; ++hc){
    __syncthreads();
    for (int k=0;k<16;++k){
      int idx = tid + (k<<8);
      int o = idx>>6, c = idx&63;
      w1s[wofs(o, c>>2) + (c&3)] = w1[(size_t)(hc*64+o)*64 + c];
      w2s[wofs(o, c>>2) + (c&3)] = w2[(size_t)o*256 + hc*64 + c];
    }
    __syncthreads();
    float hv[4][4];
    #pragma unroll
    for (int r=0;r<4;++r){ hv[r][0]=0.f; hv[r][1]=0.f; hv[r][2]=0.f; hv[r][3]=0.f; }
    #pragma unroll 4
    for (int c4=0;c4<16;++c4){
      float4 f[4], w[4];
      #pragma unroll
      for (int r=0;r<4;++r)  f[r] = *(const float4*)&f1l[(4*tr+r)*68 + (c4<<2)];
      #pragma unroll
      for (int oo=0;oo<4;++oo) w[oo] = *(const float4*)&w1s[wofs(4*to+oo, c4)];
      #pragma unroll
      for (int r=0;r<4;++r)
        #pragma unroll
        for (int oo=0;oo<4;++oo)
          hv[r][oo] += dot4(f[r], w[oo]);
    }
    #pragma unroll
    for (int r=0;r<4;++r){
      float4 v;
      float x0=hv[r][0], x1=hv[r][1], x2=hv[r][2], x3=hv[r][3];
      v.x = (x0>0.f)?x0:0.2f*x0; v.y = (x1>0.f)?x1:0.2f*x1;
      v.z = (x2>0.f)?x2:0.2f*x2; v.w = (x3>0.f)?x3:0.2f*x3;
      *(float4*)&hl[(4*tr+r)*68 + 4*to] = v;
    }
    __syncthreads();
    #pragma unroll 4
    for (int o4=0;o4<16;++o4){
      float4 h[4], w[4];
      #pragma unroll
      for (int r=0;r<4;++r)  h[r] = *(const float4*)&hl[(4*tr+r)*68 + (o4<<2)];
      #pragma unroll
      for (int oo=0;oo<4;++oo) w[oo] = *(const float4*)&w2s[wofs(4*to+oo, o4)];
      #pragma unroll
      for (int r=0;r<4;++r)
        #pragma unroll
        for (int oo=0;oo<4;++oo)
          ff[r][oo] += dot4(h[r], w[oo]);
    }
  }
  #pragma unroll
  for (int r=0;r<4;++r){
    float4 v;
    v.x = f1l[(4*tr+r)*68 + 4*to+0] + ff[r][0];
    v.y = f1l[(4*tr+r)*68 + 4*to+1] + ff[r][1];
    v.z = f1l[(4*tr+r)*68 + 4*to+2] + ff[r][2];
    v.w = f1l[(4*tr+r)*68 + 4*to+3] + ff[r][3];
    *(float4*)&t2[(rowBase + 4*tr + r)*64 + 4*to] = v;
  }
}

// ---------------------------------------------------------------- final BN2 + transpose
__global__ __launch_bounds__(256) void final_kernel(const float* __restrict__ t2,
    const float* __restrict__ bns, const float* __restrict__ bnq,
    const float* __restrict__ g2, const float* __restrict__ b2,
    float* __restrict__ out)
{
  __shared__ float tile[64*65];
  __shared__ float mu[64], rs[64], gg[64], bb[64];
  const int tid = threadIdx.x;
  const int b = blockIdx.y;
  const int n0 = blockIdx.x*64;
  if (tid < 64){
    float m = bns[tid] * (1.f/32768.f);
    float v = bnq[tid] * (1.f/32768.f) - m*m;
    mu[tid] = m; rs[tid] = 1.f/sqrtf(v + BN_EPS);
    gg[tid] = g2[tid]; bb[tid] = b2[tid];
  }
  __syncthreads();
  for (int k=0;k<16;++k){
    int idx = tid + (k<<8);
    int r = idx>>6, c = idx&63;
    float v = t2[((size_t)b*Ndim + n0 + r)*64 + c];
    tile[r*65+c] = (v - mu[c])*rs[c]*gg[c] + bb[c];
  }
  __syncthreads();
  for (int k=0;k<16;++k){
    int idx = tid + (k<<8);
    int c = idx>>6, nn = idx&63;
    out[((size_t)b*64 + c)*Ndim + n0 + nn] = tile[nn*65+c];
  }
}

extern "C" void kernel_launch(void* const* d_in, const int* in_sizes, int n_in,
                              void* d_out, int out_size, void* d_ws, size_t ws_size,
                              hipStream_t stream)
{
  (void)in_sizes; (void)n_in; (void)out_size; (void)ws_size;
  const float* x  = (const float*)d_in[0];
  const float* wq = (const float*)d_in[1];
  const float* wk = (const float*)d_in[2];
  const float* wv = (const float*)d_in[3];
  const float* w1 = (const float*)d_in[4];
  const float* w2 = (const float*)d_in[5];
  const float* g1 = (const float*)d_in[6];
  const float* b1 = (const float*)d_in[7];
  const float* g2 = (const float*)d_in[8];
  const float* b2 = (const float*)d_in[9];
  float* out = (float*)d_out;

  const size_t NE = (size_t)ROWS*64;
  float* feat = (float*)d_ws;
  float* sq   = feat + NE;
  float* Qb   = sq + ROWS;
  float* PKb  = Qb + NE;
  float* PVb  = PKb + NE;
  float* t1   = PVb + NE;
  float* t2   = t1 + NE;
  float* acc  = t2 + NE;   // 256 floats: bn1sum, bn1sq, bn2sum, bn2sq

  hipMemsetAsync(acc, 0, 256*sizeof(float), stream);
  prep_kernel<<<dim3(64,8), 256, 0, stream>>>(x, feat, sq);
  proj_kernel<<<dim3(512), 256, 0, stream>>>(feat, wq, wk, wv, Qb, PKb, PVb);
  knn_attn_kernel<<<dim3(4096), 512, 0, stream>>>(x, feat, sq, Qb, PKb, PVb, t1);
  bn_stats_kernel<<<dim3(256), 256, 0, stream>>>(t1, acc, acc+64);
  mlp_kernel<<<dim3(512), 256, 0, stream>>>(t1, w1, w2, g1, b1, acc, acc+64, t2);
  bn_stats_kernel<<<dim3(256), 256, 0, stream>>>(t2, acc+128, acc+192);
  final_kernel<<<dim3(64,8), 256, 0, stream>>>(t2, acc+128, acc+192, g2, b2, out);
}

// Round 6
// 639.884 us; speedup vs baseline: 2.6277x; 1.3655x over previous
//
#include <hip/hip_runtime.h>

#define Bdim 8
#define Cdim 64
#define Ndim 4096
#define Kdim 32
#define ROWS (Bdim*Ndim)   /* 32768 */
#define BN_EPS 1e-5f

__device__ __forceinline__ float dot4(float4 a, float4 b){
  return a.x*b.x + a.y*b.y + a.z*b.z + a.w*b.w;
}
__device__ __forceinline__ int wofs(int o, int g){ return o*64 + (((g ^ ((o>>2)&7)))<<2); }
__device__ __forceinline__ unsigned keyOf(float f){
  unsigned u = __float_as_uint(f);
  return (u & 0x80000000u) ? ~u : (u ^ 0x80000000u);
}

// ---------------------------------------------------------------- prep
__global__ __launch_bounds__(256) void prep_kernel(const float* __restrict__ x,
    float* __restrict__ feat, float* __restrict__ sq)
{
  __shared__ float tile[64*65];
  const int tid = threadIdx.x;
  const int b = blockIdx.y;
  const int n0 = blockIdx.x*64;
  for (int k=0;k<16;++k){
    int idx = tid + (k<<8);
    int c = idx>>6, nn = idx&63;
    tile[nn*65+c] = x[((size_t)b*64+c)*Ndim + n0 + nn];
  }
  __syncthreads();
  for (int k=0;k<16;++k){
    int idx = tid + (k<<8);
    int r = idx>>6, c = idx&63;
    feat[((size_t)b*Ndim + n0 + r)*64 + c] = tile[r*65+c];
  }
  if (tid < 64){
    float a = 0.f;
    #pragma unroll
    for (int c=0;c<64;++c){ float v = tile[tid*65+c]; a += v*v; }
    sq[b*Ndim + n0 + tid] = a;
  }
}

// ---------------------------------------------------------------- proj
__global__ __launch_bounds__(256) void proj_kernel(const float* __restrict__ feat,
    const float* __restrict__ wq, const float* __restrict__ wk,
    const float* __restrict__ wv,
    float* __restrict__ Qo, float* __restrict__ PKo, float* __restrict__ PVo)
{
  __shared__ __align__(16) float ftile[64*68];
  __shared__ __align__(16) float Ws[3][64*64];
  const int tid = threadIdx.x;
  const size_t rowBase = (size_t)blockIdx.x*64;
  for (int k=0;k<16;++k){
    int idx = tid + (k<<8);
    int r = idx>>6, c = idx&63;
    ftile[r*68+c] = feat[(rowBase + r)*64 + c];
  }
  {
    const float* wp[3] = {wq, wk, wv};
    for (int m=0;m<3;++m)
      for (int k=0;k<16;++k){
        int idx = tid + (k<<8);
        int o = idx>>6, c = idx&63;
        Ws[m][wofs(o, c>>2) + (c&3)] = wp[m][o*64 + c];
      }
  }
  __syncthreads();
  const int tr = tid>>4, to = tid&15;
  float* outp[3] = {Qo, PKo, PVo};
  for (int m=0;m<3;++m){
    float acc[4][4];
    #pragma unroll
    for (int r=0;r<4;++r){ acc[r][0]=0.f; acc[r][1]=0.f; acc[r][2]=0.f; acc[r][3]=0.f; }
    #pragma unroll 4
    for (int c4=0;c4<16;++c4){
      float4 f[4], w[4];
      #pragma unroll
      for (int r=0;r<4;++r)  f[r] = *(const float4*)&ftile[(4*tr+r)*68 + (c4<<2)];
      #pragma unroll
      for (int oo=0;oo<4;++oo) w[oo] = *(const float4*)&Ws[m][wofs(4*to+oo, c4)];
      #pragma unroll
      for (int r=0;r<4;++r)
        #pragma unroll
        for (int oo=0;oo<4;++oo)
          acc[r][oo] += dot4(f[r], w[oo]);
    }
    #pragma unroll
    for (int r=0;r<4;++r){
      float4 v; v.x=acc[r][0]; v.y=acc[r][1]; v.z=acc[r][2]; v.w=acc[r][3];
      *(float4*)&outp[m][(rowBase + 4*tr + r)*64 + 4*to] = v;
    }
  }
}

// ---------------------------------------------------------------- knn + attention
// 512 threads, 8 queries/WG. Coalesced x-based distances; q-values via
// wave-uniform GLOBAL loads (scalar path, no LDS). Exact top-32 per wave:
// lane-max -> ballot binary-search threshold lower bound -> candidate
// compaction (expected ~44) -> 64-lane bitonic sort on (key desc, idx asc).
// Rare >64-candidate tail falls back to the proven radix select.
__global__ __launch_bounds__(512, 4) void knn_attn_kernel(
    const float* __restrict__ x,
    const float* __restrict__ feat, const float* __restrict__ sq,
    const float* __restrict__ Qm, const float* __restrict__ PKm, const float* __restrict__ PVm,
    float* __restrict__ t1)
{
  __shared__ __align__(16) unsigned char smem[40992];
  float*    chunkF = (float*)smem;                 // [4][2048] 32 KB (distance phase)
  unsigned* candK  = (unsigned*)smem;              // [8][64]  (alias, selection)
  int*      candI  = (int*)(smem + 2048);          // [8][64]
  int*      outIdx = (int*)(smem + 4096);          // [8][32]
  float*    enS    = (float*)(smem + 5120);        // [8][128]
  unsigned* histU  = (unsigned*)(smem + 9216);     // [8][256] (fallback only)
  int*      tieL   = (int*)(smem + 17408);         // [8][64]  (fallback only)
  float*    fnS    = (float*)(smem + 32768);       // [8][64]
  float*    qvS    = (float*)(smem + 34816);       // [8][64]
  float*    pknS   = (float*)(smem + 36864);       // [8][64]
  float*    pvnS   = (float*)(smem + 38912);       // [8][64]
  float*    sqnS   = (float*)(smem + 40960);       // [8]

  const int tid = threadIdx.x;
  const int lane = tid & 63;
  const int w = tid >> 6;
  const int blk = blockIdx.x;
  const int b  = blk & 7;                          // XCD-locality swizzle
  const int n0 = (blk >> 3) << 3;                  // 8 queries
  const float* xb = x + (size_t)b*64*Ndim;

  {
    int j = tid>>6, c = tid&63;
    size_t ro = ((size_t)b*Ndim + n0 + j)*64 + c;
    fnS[tid]  = feat[ro];
    qvS[tid]  = Qm[ro];
    pknS[tid] = PKm[ro];
    pvnS[tid] = PVm[ro];
    if (tid < 8) sqnS[tid] = sq[b*Ndim + n0 + tid];
  }
  __syncthreads();

  unsigned kk[64];

  #pragma unroll
  for (int g=0; g<2; ++g){
    const int m0 = (g<<11) + (tid<<2);
    float acc[8][4];
    #pragma unroll
    for (int q=0;q<8;++q){ acc[q][0]=0.f; acc[q][1]=0.f; acc[q][2]=0.f; acc[q][3]=0.f; }
    #pragma unroll 4
    for (int c=0;c<64;++c){
      float4 xm = *(const float4*)&xb[(size_t)c*Ndim + m0];        // coalesced
      float4 qA = *(const float4*)&xb[(size_t)c*Ndim + n0];        // wave-uniform -> scalar
      float4 qB = *(const float4*)&xb[(size_t)c*Ndim + n0 + 4];
      const float qs[8] = {qA.x,qA.y,qA.z,qA.w,qB.x,qB.y,qB.z,qB.w};
      #pragma unroll
      for (int q=0;q<8;++q){
        acc[q][0] += qs[q]*xm.x; acc[q][1] += qs[q]*xm.y;
        acc[q][2] += qs[q]*xm.z; acc[q][3] += qs[q]*xm.w;
      }
    }
    float4 sqm4 = *(const float4*)&sq[b*Ndim + m0];
    #pragma unroll
    for (int half=0; half<2; ++half){
      __syncthreads();   // chunk free (or consumed by previous half)
      #pragma unroll
      for (int qq=0;qq<4;++qq){
        int q = (half<<2)+qq;
        float sqn_q = sqnS[q];
        float4 v;
        v.x = (2.f*acc[q][0]-sqn_q)-sqm4.x;
        v.y = (2.f*acc[q][1]-sqn_q)-sqm4.y;
        v.z = (2.f*acc[q][2]-sqn_q)-sqm4.z;
        v.w = (2.f*acc[q][3]-sqn_q)-sqm4.w;
        *(float4*)&chunkF[(qq<<11) + (tid<<2)] = v;
      }
      __syncthreads();
      if ((w>>2) == half){
        const int wq = w & 3;
        #pragma unroll
        for (int i=0;i<32;++i)
          kk[(g<<5)+i] = keyOf(chunkF[(wq<<11)+(i<<6)+lane]);
      }
    }
  }
  __syncthreads();   // chunk dead -> selection arrays may alias it

  // defensive pre-fill: unwritten slots stay VALID indices
  if (lane < 32) outIdx[(w<<5)+lane] = n0 + w;
  tieL[(w<<6)+lane] = n0 + w;

  // ---- exact top-32, wave w handles query w, keys in registers
  {
    // 1) lane-local max
    unsigned lmax = kk[0];
    #pragma unroll
    for (int j=1;j<64;++j) lmax = lmax > kk[j] ? lmax : kk[j];
    // 2) largest T with >=32 lanes having laneMax >= T  => T <= true 32nd key
    unsigned T = 0u;
    #pragma unroll
    for (int bit=31; bit>=0; --bit){
      unsigned cand = T | (1u << bit);
      int cnt = (int)__popcll(__ballot(lmax >= cand));
      if (cnt >= 32) T = cand;
    }
    // 3) compact candidates (key >= T); all true top-32 survive by construction
    int base = 0;
    #pragma unroll 4
    for (int j=0;j<64;++j){
      bool isc = (kk[j] >= T);
      unsigned long long mk = __ballot(isc);
      if (mk){
        if (isc){
          int slot = base + (int)__popcll(mk & ((1ull<<lane)-1ull));
          if (slot < 64){
            candK[(w<<6)+slot] = kk[j];
            candI[(w<<6)+slot] = ((j>>5)<<11)+((j&31)<<6)+lane;
          }
        }
        base += (int)__popcll(mk);
      }
    }
    const int S = base;   // >= 32 guaranteed
    __threadfence_block();
    if (S <= 64){
      // 4) bitonic sort 64 lanes, descending (key, ~idx) -> stable top_k order
      unsigned long long C = 0ull;
      if (lane < S)
        C = ((unsigned long long)candK[(w<<6)+lane] << 32) |
            (unsigned long long)(~(unsigned)candI[(w<<6)+lane]);
      #pragma unroll
      for (int k2=2; k2<=64; k2<<=1){
        #pragma unroll
        for (int j2=k2>>1; j2>=1; j2>>=1){
          unsigned long long P = (unsigned long long)__shfl_xor((long long)C, j2, 64);
          bool lowIdx  = ((lane & j2) == 0);
          bool keepMax = (lowIdx == ((lane & k2) == 0));
          unsigned long long mx = C > P ? C : P;
          unsigned long long mn = C > P ? P : C;
          C = keepMax ? mx : mn;
        }
      }
      if (lane < 32) outIdx[(w<<5)+lane] = (int)(~(unsigned)(C & 0xFFFFFFFFull)) & (Ndim-1);
    } else {
      // ---- rare fallback: proven radix select (round-5 code) ----
      unsigned prefix = 0u, want = 32u;
      for (int pass=0; pass<4; ++pass){
        const int shift = 24-(pass<<3);
        histU[(w<<8)+lane] = 0u; histU[(w<<8)+64+lane] = 0u;
        histU[(w<<8)+128+lane] = 0u; histU[(w<<8)+192+lane] = 0u;
        __threadfence_block();
        const unsigned maskAb = (pass==0) ? 0u : (0xFFFFFFFFu << (32-(pass<<3)));
        for (int i=0;i<64;++i){
          unsigned u = kk[i];
          if ((u & maskAb) == prefix) atomicAdd(&histU[(w<<8)+((u>>shift)&255u)], 1u);
        }
        __threadfence_block();
        uint4 cc = *(const uint4*)&histU[(w<<8)+(lane<<2)];
        unsigned sum4 = cc.x+cc.y+cc.z+cc.w;
        unsigned s = sum4;
        for (int off=1; off<64; off<<=1){
          unsigned t = (unsigned)__shfl_down((int)s, off, 64);
          if (lane + off < 64) s += t;
        }
        unsigned S0=s, S1=s-cc.x, S2=S1-cc.y, S3=S2-cc.z, S4=s-sum4;
        unsigned val = 0u;
        if (S0 >= want && S1 < want) val = ((unsigned)((lane<<2)+0) << 16) | (want - S1);
        if (S1 >= want && S2 < want) val = ((unsigned)((lane<<2)+1) << 16) | (want - S2);
        if (S2 >= want && S3 < want) val = ((unsigned)((lane<<2)+2) << 16) | (want - S3);
        if (S3 >= want && S4 < want) val = ((unsigned)((lane<<2)+3) << 16) | (want - S4);
        for (int off=32; off>=1; off>>=1) val |= (unsigned)__shfl_xor((int)val, off, 64);
        unsigned bin = val >> 16; want = val & 0xFFFFu;
        if (val == 0u){ bin = 255u; want = 1u; }
        prefix |= bin << shift;
      }
      const unsigned Tr = prefix;
      int rb = 0, tb = 0;
      for (int i=0;i<64;++i){
        const int m = ((i>>5)<<11) + ((i&31)<<6) + lane;
        unsigned u = kk[i];
        unsigned long long mg = __ballot(u > Tr);
        unsigned long long mt = __ballot(u == Tr);
        unsigned long long below = (1ull << lane) - 1ull;
        if (u > Tr){
          int slot = rb + (int)__popcll(mg & below);
          if (slot < 32) outIdx[(w<<5)+slot] = m;
        } else if (u == Tr){
          int slot = tb + (int)__popcll(mt & below);
          if (slot < 64) tieL[(w<<6)+slot] = m;
        }
        rb += (int)__popcll(mg);
        tb += (int)__popcll(mt);
      }
      __threadfence_block();
      int need = 32 - rb;
      if (need > 0 && lane < need){
        int slot = rb + lane;
        if (slot >= 0 && slot < 32) outIdx[(w<<5)+slot] = tieL[(w<<6)+lane];
      }
    }
  }
  __syncthreads();

  // ---- attention energies: 1024 tasks = 8q x 4h x 32k
  #pragma unroll
  for (int p=0;p<2;++p){
    int task = tid + (p<<9);
    int jn = task>>7, h = (task>>5)&3, k2 = task&31;
    int mj = outIdx[(jn<<5)+k2] & (Ndim-1);
    const float4* pk4 = (const float4*)(PKm + ((size_t)b*Ndim + mj)*64 + (h<<4));
    const float4* qq4 = (const float4*)&qvS[(jn<<6)+(h<<4)];
    const float4* nn4 = (const float4*)&pknS[(jn<<6)+(h<<4)];
    float e = 0.f;
    #pragma unroll
    for (int d=0;d<4;++d){
      float4 kv = pk4[d], qq = qq4[d], nn = nn4[d];
      e += qq.x*(kv.x-nn.x) + qq.y*(kv.y-nn.y) + qq.z*(kv.z-nn.z) + qq.w*(kv.w-nn.w);
    }
    enS[(jn<<7)+(h<<5)+k2] = e * 0.25f;
  }
  __syncthreads();
  if (tid < 32){
    int jn = tid>>2, h = tid&3;
    float* ep = &enS[(jn<<7)+(h<<5)];
    float mx = -1e30f;
    for (int k2=0;k2<32;++k2) mx = fmaxf(mx, ep[k2]);
    float ssum = 0.f;
    for (int k2=0;k2<32;++k2){ float ex = expf(ep[k2]-mx); ep[k2] = ex; ssum += ex; }
    float inv = 1.f/ssum;
    for (int k2=0;k2<32;++k2) ep[k2] *= inv;
  }
  __syncthreads();
  {
    int jn = tid>>6, c = tid&63, h = c>>4;
    float a2 = 0.f;
    #pragma unroll 8
    for (int k2=0;k2<32;++k2){
      int mj = outIdx[(jn<<5)+k2] & (Ndim-1);
      a2 += enS[(jn<<7)+(h<<5)+k2] * (PVm[((size_t)b*Ndim + mj)*64 + c] - pvnS[(jn<<6)+c]);
    }
    t1[((size_t)b*Ndim + n0 + jn)*64 + c] = fnS[(jn<<6)+c] + a2;
  }
}

// ---------------------------------------------------------------- BN stats
__global__ __launch_bounds__(256) void bn_stats_kernel(const float* __restrict__ in,
    float* __restrict__ sAcc, float* __restrict__ qAcc)
{
  __shared__ float ps[256], ps2[256];
  const int tid = threadIdx.x;
  const int c = tid&63, rg = tid>>6;
  const size_t base = (size_t)blockIdx.x*128;
  float s = 0.f, s2 = 0.f;
  for (int i=0;i<32;++i){
    float v = in[(base + rg + (size_t)i*4)*64 + c];
    s += v; s2 += v*v;
  }
  ps[tid] = s; ps2[tid] = s2;
  __syncthreads();
  if (tid < 64){
    float S  = ps[tid]+ps[tid+64]+ps[tid+128]+ps[tid+192];
    float S2 = ps2[tid]+ps2[tid+64]+ps2[tid+128]+ps2[tid+192];
    atomicAdd(&sAcc[tid], S);
    atomicAdd(&qAcc[tid], S2);
  }
}

// ---------------------------------------------------------------- MLP
__global__ __launch_bounds__(256) void mlp_kernel(const float* __restrict__ t1,
    const float* __restrict__ w1, const float* __restrict__ w2,
    const float* __restrict__ g1, const float* __restrict__ b1,
    const float* __restrict__ bns, const float* __restrict__ bnq,
    float* __restrict__ t2)
{
  __shared__ __align__(16) float f1l[64*68];
  __shared__ __align__(16) float hl[64*68];
  __shared__ __align__(16) float w1s[64*64];
  __shared__ __align__(16) float w2s[64*64];
  __shared__ float mu[64], rs[64], gg[64], bb[64];
  const int tid = threadIdx.x;
  if (tid < 64){
    float m = bns[tid] * (1.f/32768.f);
    float v = bnq[tid] * (1.f/32768.f) - m*m;
    mu[tid] = m; rs[tid] = 1.f/sqrtf(v + BN_EPS);
    gg[tid] = g1[tid]; bb[tid] = b1[tid];
  }
  __syncthreads();
  const size_t rowBase = (size_t)blockIdx.x*64;
  for (int k=0;k<16;++k){
    int idx = tid + (k<<8);
    int r = idx>>6, c = idx&63;
    float v = t1[(rowBase + r)*64 + c];
    f1l[r*68+c] = (v - mu[c])*rs[c]*gg[c] + bb[c];
  }
  const int tr = tid>>4, to = tid&15;
  float ff[4][4];
  #pragma unroll
  for (int r=0;r<4;++r){ ff[r][0]=0.f; ff[r][1]=0.f; ff[r][2]=0.f; ff[r][3]=0.f; }

  for (int hc=0; hc<4; ++hc){
    __syncthreads();
    for (int k=0;k<16;++k){
      int idx = tid + (k<<8);
      int o = idx>>6, c = idx&63;
      w1s[wofs(o, c>>2) + (c&3)] = w1[(size_t)(hc*64+o)*64 + c];
      w2s[wofs(o, c>>2) + (c&3)] = w2[(size_t)o*256 + hc*64 + c];
    }
    __syncthreads();
    float hv[4][4];
    #pragma unroll
    for (int r=0;r<4;++r){ hv[r][0]=0.f; hv[r][1]=0.f; hv[r][2]=0.f; hv[r][3]=0.f; }
    #pragma unroll 4
    for (int c4=0;c4<16;++c4){
      float4 f[4], w[4];
      #pragma unroll
      for (int r=0;r<4;++r)  f[r] = *(const float4*)&f1l[(4*tr+r)*68 + (c4<<2)];
      #pragma unroll
      for (int oo=0;oo<4;++oo) w[oo] = *(const float4*)&w1s[wofs(4*to+oo, c4)];
      #pragma unroll
      for (int r=0;r<4;++r)
        #pragma unroll
        for (int oo=0;oo<4;++oo)
          hv[r][oo] += dot4(f[r], w[oo]);
    }
    #pragma unroll
    for (int r=0;r<4;++r){
      float4 v;
      float x0=hv[r][0], x1=hv[r][1], x2=hv[r][2], x3=hv[r][3];
      v.x = (x0>0.f)?x0:0.2f*x0; v.y = (x1>0.f)?x1:0.2f*x1;
      v.z = (x2>0.f)?x2:0.2f*x2; v.w = (x3>0.f)?x3:0.2f*x3;
      *(float4*)&hl[(4*tr+r)*68 + 4*to] = v;
    }
    __syncthreads();
    #pragma unroll 4
    for (int o4=0;o4<16;++o4){
      float4 h[4], w[4];
      #pragma unroll
      for (int r=0;r<4;++r)  h[r] = *(const float4*)&hl[(4*tr+r)*68 + (o4<<2)];
      #pragma unroll
      for (int oo=0;oo<4;++oo) w[oo] = *(const float4*)&w2s[wofs(4*to+oo, o4)];
      #pragma unroll
      for (int r=0;r<4;++r)
        #pragma unroll
        for (int oo=0;oo<4;++oo)
          ff[r][oo] += dot4(h[r], w[oo]);
    }
  }
  #pragma unroll
  for (int r=0;r<4;++r){
    float4 v;
    v.x = f1l[(4*tr+r)*68 + 4*to+0] + ff[r][0];
    v.y = f1l[(4*tr+r)*68 + 4*to+1] + ff[r][1];
    v.z = f1l[(4*tr+r)*68 + 4*to+2] + ff[r][2];
    v.w = f1l[(4*tr+r)*68 + 4*to+3] + ff[r][3];
    *(float4*)&t2[(rowBase + 4*tr + r)*64 + 4*to] = v;
  }
}

// ---------------------------------------------------------------- final BN2 + transpose
__global__ __launch_bounds__(256) void final_kernel(const float* __restrict__ t2,
    const float* __restrict__ bns, const float* __restrict__ bnq,
    const float* __restrict__ g2, const float* __restrict__ b2,
    float* __restrict__ out)
{
  __shared__ float tile[64*65];
  __shared__ float mu[64], rs[64], gg[64], bb[64];
  const int tid = threadIdx.x;
  const int b = blockIdx.y;
  const int n0 = blockIdx.x*64;
  if (tid < 64){
    float m = bns[tid] * (1.f/32768.f);
    float v = bnq[tid] * (1.f/32768.f) - m*m;
    mu[tid] = m; rs[tid] = 1.f/sqrtf(v + BN_EPS);
    gg[tid] = g2[tid]; bb[tid] = b2[tid];
  }
  __syncthreads();
  for (int k=0;k<16;++k){
    int idx = tid + (k<<8);
    int r = idx>>6, c = idx&63;
    float v = t2[((size_t)b*Ndim + n0 + r)*64 + c];
    tile[r*65+c] = (v - mu[c])*rs[c]*gg[c] + bb[c];
  }
  __syncthreads();
  for (int k=0;k<16;++k){
    int idx = tid + (k<<8);
    int c = idx>>6, nn = idx&63;
    out[((size_t)b*64 + c)*Ndim + n0 + nn] = tile[nn*65+c];
  }
}

extern "C" void kernel_launch(void* const* d_in, const int* in_sizes, int n_in,
                              void* d_out, int out_size, void* d_ws, size_t ws_size,
                              hipStream_t stream)
{
  (void)in_sizes; (void)n_in; (void)out_size; (void)ws_size;
  const float* x  = (const float*)d_in[0];
  const float* wq = (const float*)d_in[1];
  const float* wk = (const float*)d_in[2];
  const float* wv = (const float*)d_in[3];
  const float* w1 = (const float*)d_in[4];
  const float* w2 = (const float*)d_in[5];
  const float* g1 = (const float*)d_in[6];
  const float* b1 = (const float*)d_in[7];
  const float* g2 = (const float*)d_in[8];
  const float* b2 = (const float*)d_in[9];
  float* out = (float*)d_out;

  const size_t NE = (size_t)ROWS*64;
  float* feat = (float*)d_ws;
  float* sq   = feat + NE;
  float* Qb   = sq + ROWS;
  float* PKb  = Qb + NE;
  float* PVb  = PKb + NE;
  float* t1   = PVb + NE;
  float* t2   = t1 + NE;
  float* acc  = t2 + NE;   // 256 floats: bn1sum, bn1sq, bn2sum, bn2sq

  hipMemsetAsync(acc, 0, 256*sizeof(float), stream);
  prep_kernel<<<dim3(64,8), 256, 0, stream>>>(x, feat, sq);
  proj_kernel<<<dim3(512), 256, 0, stream>>>(feat, wq, wk, wv, Qb, PKb, PVb);
  knn_attn_kernel<<<dim3(4096), 512, 0, stream>>>(x, feat, sq, Qb, PKb, PVb, t1);
  bn_stats_kernel<<<dim3(256), 256, 0, stream>>>(t1, acc, acc+64);
  mlp_kernel<<<dim3(512), 256, 0, stream>>>(t1, w1, w2, g1, b1, acc, acc+64, t2);
  bn_stats_kernel<<<dim3(256), 256, 0, stream>>>(t2, acc+128, acc+192);
  final_kernel<<<dim3(64,8), 256, 0, stream>>>(t2, acc+128, acc+192, g2, b2, out);
}

// Round 7
// 478.109 us; speedup vs baseline: 3.5169x; 1.3384x over previous
//
#include <hip/hip_runtime.h>

#define Bdim 8
#define Cdim 64
#define Ndim 4096
#define Kdim 32
#define ROWS (Bdim*Ndim)   /* 32768 */
#define BN_EPS 1e-5f

__device__ __forceinline__ float dot4(float4 a, float4 b){
  return a.x*b.x + a.y*b.y + a.z*b.z + a.w*b.w;
}
__device__ __forceinline__ int wofs(int o, int g){ return o*64 + (((g ^ ((o>>2)&7)))<<2); }
__device__ __forceinline__ unsigned keyOf(float f){
  unsigned u = __float_as_uint(f);
  return (u & 0x80000000u) ? ~u : (u ^ 0x80000000u);
}

// ---------------------------------------------------------------- prep
__global__ __launch_bounds__(256) void prep_kernel(const float* __restrict__ x,
    float* __restrict__ feat, float* __restrict__ sq)
{
  __shared__ float tile[64*65];
  const int tid = threadIdx.x;
  const int b = blockIdx.y;
  const int n0 = blockIdx.x*64;
  for (int k=0;k<16;++k){
    int idx = tid + (k<<8);
    int c = idx>>6, nn = idx&63;
    tile[nn*65+c] = x[((size_t)b*64+c)*Ndim + n0 + nn];
  }
  __syncthreads();
  for (int k=0;k<16;++k){
    int idx = tid + (k<<8);
    int r = idx>>6, c = idx&63;
    feat[((size_t)b*Ndim + n0 + r)*64 + c] = tile[r*65+c];
  }
  if (tid < 64){
    float a = 0.f;
    #pragma unroll
    for (int c=0;c<64;++c){ float v = tile[tid*65+c]; a += v*v; }
    sq[b*Ndim + n0 + tid] = a;
  }
}

// ---------------------------------------------------------------- proj
__global__ __launch_bounds__(256) void proj_kernel(const float* __restrict__ feat,
    const float* __restrict__ wq, const float* __restrict__ wk,
    const float* __restrict__ wv,
    float* __restrict__ Qo, float* __restrict__ PKo, float* __restrict__ PVo)
{
  __shared__ __align__(16) float ftile[64*68];
  __shared__ __align__(16) float Ws[3][64*64];
  const int tid = threadIdx.x;
  const size_t rowBase = (size_t)blockIdx.x*64;
  for (int k=0;k<16;++k){
    int idx = tid + (k<<8);
    int r = idx>>6, c = idx&63;
    ftile[r*68+c] = feat[(rowBase + r)*64 + c];
  }
  {
    const float* wp[3] = {wq, wk, wv};
    for (int m=0;m<3;++m)
      for (int k=0;k<16;++k){
        int idx = tid + (k<<8);
        int o = idx>>6, c = idx&63;
        Ws[m][wofs(o, c>>2) + (c&3)] = wp[m][o*64 + c];
      }
  }
  __syncthreads();
  const int tr = tid>>4, to = tid&15;
  float* outp[3] = {Qo, PKo, PVo};
  for (int m=0;m<3;++m){
    float acc[4][4];
    #pragma unroll
    for (int r=0;r<4;++r){ acc[r][0]=0.f; acc[r][1]=0.f; acc[r][2]=0.f; acc[r][3]=0.f; }
    #pragma unroll 4
    for (int c4=0;c4<16;++c4){
      float4 f[4], w[4];
      #pragma unroll
      for (int r=0;r<4;++r)  f[r] = *(const float4*)&ftile[(4*tr+r)*68 + (c4<<2)];
      #pragma unroll
      for (int oo=0;oo<4;++oo) w[oo] = *(const float4*)&Ws[m][wofs(4*to+oo, c4)];
      #pragma unroll
      for (int r=0;r<4;++r)
        #pragma unroll
        for (int oo=0;oo<4;++oo)
          acc[r][oo] += dot4(f[r], w[oo]);
    }
    #pragma unroll
    for (int r=0;r<4;++r){
      float4 v; v.x=acc[r][0]; v.y=acc[r][1]; v.z=acc[r][2]; v.w=acc[r][3];
      *(float4*)&outp[m][(rowBase + 4*tr + r)*64 + 4*to] = v;
    }
  }
}

// ---------------------------------------------------------------- knn + attention
// 512 threads, 8 queries/WG. Coalesced x-based distances; q-values via
// wave-uniform global loads. Exact top-32 per wave: lane-max -> ballot
// binary-search threshold lower bound -> candidate compaction -> bitonic
// sort. S>64 fallback: register-only exact threshold + ballot gather.
// ALL kk[] loops fully unrolled (dynamic indexing would spill kk to scratch:
// round-6 counters showed 532 MB scratch writes from one #pragma unroll 4).
__global__ __launch_bounds__(512, 4) void knn_attn_kernel(
    const float* __restrict__ x,
    const float* __restrict__ feat, const float* __restrict__ sq,
    const float* __restrict__ Qm, const float* __restrict__ PKm, const float* __restrict__ PVm,
    float* __restrict__ t1)
{
  __shared__ __align__(16) unsigned char smem[40992];
  float*    chunkF = (float*)smem;                 // [4][2048] 32 KB (distance phase)
  unsigned* candK  = (unsigned*)smem;              // [8][64]  (alias, selection)
  int*      candI  = (int*)(smem + 2048);          // [8][64]
  int*      outIdx = (int*)(smem + 4096);          // [8][32]
  float*    enS    = (float*)(smem + 5120);        // [8][128]
  float*    fnS    = (float*)(smem + 32768);       // [8][64]
  float*    qvS    = (float*)(smem + 34816);       // [8][64]
  float*    pknS   = (float*)(smem + 36864);       // [8][64]
  float*    pvnS   = (float*)(smem + 38912);       // [8][64]
  float*    sqnS   = (float*)(smem + 40960);       // [8]

  const int tid = threadIdx.x;
  const int lane = tid & 63;
  const int w = tid >> 6;
  const int blk = blockIdx.x;
  const int b  = blk & 7;                          // XCD-locality swizzle
  const int n0 = (blk >> 3) << 3;                  // 8 queries
  const float* xb = x + (size_t)b*64*Ndim;

  {
    int j = tid>>6, c = tid&63;
    size_t ro = ((size_t)b*Ndim + n0 + j)*64 + c;
    fnS[tid]  = feat[ro];
    qvS[tid]  = Qm[ro];
    pknS[tid] = PKm[ro];
    pvnS[tid] = PVm[ro];
    if (tid < 8) sqnS[tid] = sq[b*Ndim + n0 + tid];
  }
  __syncthreads();

  unsigned kk[64];

  #pragma unroll
  for (int g=0; g<2; ++g){
    const int m0 = (g<<11) + (tid<<2);
    float acc[8][4];
    #pragma unroll
    for (int q=0;q<8;++q){ acc[q][0]=0.f; acc[q][1]=0.f; acc[q][2]=0.f; acc[q][3]=0.f; }
    #pragma unroll 4
    for (int c=0;c<64;++c){
      float4 xm = *(const float4*)&xb[(size_t)c*Ndim + m0];        // coalesced
      float4 qA = *(const float4*)&xb[(size_t)c*Ndim + n0];        // wave-uniform -> scalar
      float4 qB = *(const float4*)&xb[(size_t)c*Ndim + n0 + 4];
      const float qs[8] = {qA.x,qA.y,qA.z,qA.w,qB.x,qB.y,qB.z,qB.w};
      #pragma unroll
      for (int q=0;q<8;++q){
        acc[q][0] += qs[q]*xm.x; acc[q][1] += qs[q]*xm.y;
        acc[q][2] += qs[q]*xm.z; acc[q][3] += qs[q]*xm.w;
      }
    }
    float4 sqm4 = *(const float4*)&sq[b*Ndim + m0];
    #pragma unroll
    for (int half=0; half<2; ++half){
      __syncthreads();   // chunk free (or consumed by previous half)
      #pragma unroll
      for (int qq=0;qq<4;++qq){
        int q = (half<<2)+qq;
        float sqn_q = sqnS[q];
        float4 v;
        v.x = (2.f*acc[q][0]-sqn_q)-sqm4.x;
        v.y = (2.f*acc[q][1]-sqn_q)-sqm4.y;
        v.z = (2.f*acc[q][2]-sqn_q)-sqm4.z;
        v.w = (2.f*acc[q][3]-sqn_q)-sqm4.w;
        *(float4*)&chunkF[(qq<<11) + (tid<<2)] = v;
      }
      __syncthreads();
      if ((w>>2) == half){
        const int wq = w & 3;
        #pragma unroll
        for (int i=0;i<32;++i)
          kk[(g<<5)+i] = keyOf(chunkF[(wq<<11)+(i<<6)+lane]);
      }
    }
  }
  __syncthreads();   // chunk dead -> selection arrays may alias it

  // defensive pre-fill: unwritten slots stay VALID indices
  if (lane < 32) outIdx[(w<<5)+lane] = n0 + w;

  // ---- exact top-32, wave w handles query w, keys in registers
  {
    // 1) lane-local max
    unsigned lmax = kk[0];
    #pragma unroll
    for (int j=1;j<64;++j) lmax = lmax > kk[j] ? lmax : kk[j];
    // 2) largest T with >=32 lanes having laneMax >= T  => T <= true 32nd key
    unsigned T = 0u;
    #pragma unroll
    for (int bit=31; bit>=0; --bit){
      unsigned cand = T | (1u << bit);
      int cnt = (int)__popcll(__ballot(lmax >= cand));
      if (cnt >= 32) T = cand;
    }
    // 3) compact candidates (key >= T); all true top-32 survive by construction
    int base = 0;
    #pragma unroll
    for (int j=0;j<64;++j){
      bool isc = (kk[j] >= T);
      unsigned long long mk = __ballot(isc);
      if (isc){
        int slot = base + (int)__popcll(mk & ((1ull<<lane)-1ull));
        if (slot < 64){
          candK[(w<<6)+slot] = kk[j];
          candI[(w<<6)+slot] = ((j>>5)<<11)+((j&31)<<6)+lane;
        }
      }
      base += (int)__popcll(mk);
    }
    const int S = base;   // >= 32 guaranteed
    __threadfence_block();
    if (S <= 64){
      // 4) bitonic sort 64 lanes, descending (key, ~idx) -> stable top_k order
      unsigned long long C = 0ull;
      if (lane < S)
        C = ((unsigned long long)candK[(w<<6)+lane] << 32) |
            (unsigned long long)(~(unsigned)candI[(w<<6)+lane]);
      #pragma unroll
      for (int k2=2; k2<=64; k2<<=1){
        #pragma unroll
        for (int j2=k2>>1; j2>=1; j2>>=1){
          unsigned long long P = (unsigned long long)__shfl_xor((long long)C, j2, 64);
          bool lowIdx  = ((lane & j2) == 0);
          bool keepMax = (lowIdx == ((lane & k2) == 0));
          unsigned long long mx = C > P ? C : P;
          unsigned long long mn = C > P ? P : C;
          C = keepMax ? mx : mn;
        }
      }
      if (lane < 32) outIdx[(w<<5)+lane] = (int)(~(unsigned)(C & 0xFFFFFFFFull)) & (Ndim-1);
    } else {
      // ---- rare fallback (register-only, fully unrolled, no LDS) ----
      // exact 32nd-largest key over all 4096 keys via ballot binary search
      unsigned Te = 0u;
      for (int bit=31; bit>=0; --bit){
        unsigned cand = Te | (1u << bit);
        int lc = 0;
        #pragma unroll
        for (int j=0;j<64;++j) lc += (kk[j] >= cand) ? 1 : 0;
        #pragma unroll
        for (int off=1; off<64; off<<=1) lc += __shfl_xor(lc, off, 64);
        if (lc >= 32) Te = cand;
      }
      // gather: all keys > Te (ascending m), then ==Te ties ascending m
      const unsigned long long below = (1ull << lane) - 1ull;
      int b2 = 0;
      #pragma unroll
      for (int j=0;j<64;++j){
        unsigned u = kk[j];
        unsigned long long mg = __ballot(u > Te);
        if (u > Te){
          int slot = b2 + (int)__popcll(mg & below);
          if (slot < 32) outIdx[(w<<5)+slot] = ((j>>5)<<11)+((j&31)<<6)+lane;
        }
        b2 += (int)__popcll(mg);
      }
      #pragma unroll
      for (int j=0;j<64;++j){
        unsigned u = kk[j];
        unsigned long long mt = __ballot(u == Te);
        if (u == Te){
          int slot = b2 + (int)__popcll(mt & below);
          if (slot < 32) outIdx[(w<<5)+slot] = ((j>>5)<<11)+((j&31)<<6)+lane;
        }
        b2 += (int)__popcll(mt);
      }
    }
  }
  __syncthreads();

  // ---- attention energies: 1024 tasks = 8q x 4h x 32k
  #pragma unroll
  for (int p=0;p<2;++p){
    int task = tid + (p<<9);
    int jn = task>>7, h = (task>>5)&3, k2 = task&31;
    int mj = outIdx[(jn<<5)+k2] & (Ndim-1);
    const float4* pk4 = (const float4*)(PKm + ((size_t)b*Ndim + mj)*64 + (h<<4));
    const float4* qq4 = (const float4*)&qvS[(jn<<6)+(h<<4)];
    const float4* nn4 = (const float4*)&pknS[(jn<<6)+(h<<4)];
    float e = 0.f;
    #pragma unroll
    for (int d=0;d<4;++d){
      float4 kv = pk4[d], qq = qq4[d], nn = nn4[d];
      e += qq.x*(kv.x-nn.x) + qq.y*(kv.y-nn.y) + qq.z*(kv.z-nn.z) + qq.w*(kv.w-nn.w);
    }
    enS[(jn<<7)+(h<<5)+k2] = e * 0.25f;
  }
  __syncthreads();
  if (tid < 32){
    int jn = tid>>2, h = tid&3;
    float* ep = &enS[(jn<<7)+(h<<5)];
    float mx = -1e30f;
    for (int k2=0;k2<32;++k2) mx = fmaxf(mx, ep[k2]);
    float ssum = 0.f;
    for (int k2=0;k2<32;++k2){ float ex = expf(ep[k2]-mx); ep[k2] = ex; ssum += ex; }
    float inv = 1.f/ssum;
    for (int k2=0;k2<32;++k2) ep[k2] *= inv;
  }
  __syncthreads();
  {
    int jn = tid>>6, c = tid&63, h = c>>4;
    float a2 = 0.f;
    #pragma unroll 8
    for (int k2=0;k2<32;++k2){
      int mj = outIdx[(jn<<5)+k2] & (Ndim-1);
      a2 += enS[(jn<<7)+(h<<5)+k2] * (PVm[((size_t)b*Ndim + mj)*64 + c] - pvnS[(jn<<6)+c]);
    }
    t1[((size_t)b*Ndim + n0 + jn)*64 + c] = fnS[(jn<<6)+c] + a2;
  }
}

// ---------------------------------------------------------------- BN stats
__global__ __launch_bounds__(256) void bn_stats_kernel(const float* __restrict__ in,
    float* __restrict__ sAcc, float* __restrict__ qAcc)
{
  __shared__ float ps[256], ps2[256];
  const int tid = threadIdx.x;
  const int c = tid&63, rg = tid>>6;
  const size_t base = (size_t)blockIdx.x*128;
  float s = 0.f, s2 = 0.f;
  for (int i=0;i<32;++i){
    float v = in[(base + rg + (size_t)i*4)*64 + c];
    s += v; s2 += v*v;
  }
  ps[tid] = s; ps2[tid] = s2;
  __syncthreads();
  if (tid < 64){
    float S  = ps[tid]+ps[tid+64]+ps[tid+128]+ps[tid+192];
    float S2 = ps2[tid]+ps2[tid+64]+ps2[tid+128]+ps2[tid+192];
    atomicAdd(&sAcc[tid], S);
    atomicAdd(&qAcc[tid], S2);
  }
}

// ---------------------------------------------------------------- MLP
__global__ __launch_bounds__(256) void mlp_kernel(const float* __restrict__ t1,
    const float* __restrict__ w1, const float* __restrict__ w2,
    const float* __restrict__ g1, const float* __restrict__ b1,
    const float* __restrict__ bns, const float* __restrict__ bnq,
    float* __restrict__ t2)
{
  __shared__ __align__(16) float f1l[64*68];
  __shared__ __align__(16) float hl[64*68];
  __shared__ __align__(16) float w1s[64*64];
  __shared__ __align__(16) float w2s[64*64];
  __shared__ float mu[64], rs[64], gg[64], bb[64];
  const int tid = threadIdx.x;
  if (tid < 64){
    float m = bns[tid] * (1.f/32768.f);
    float v = bnq[tid] * (1.f/32768.f) - m*m;
    mu[tid] = m; rs[tid] = 1.f/sqrtf(v + BN_EPS);
    gg[tid] = g1[tid]; bb[tid] = b1[tid];
  }
  __syncthreads();
  const size_t rowBase = (size_t)blockIdx.x*64;
  for (int k=0;k<16;++k){
    int idx = tid + (k<<8);
    int r = idx>>6, c = idx&63;
    float v = t1[(rowBase + r)*64 + c];
    f1l[r*68+c] = (v - mu[c])*rs[c]*gg[c] + bb[c];
  }
  const int tr = tid>>4, to = tid&15;
  float ff[4][4];
  #pragma unroll
  for (int r=0;r<4;++r){ ff[r][0]=0.f; ff[r][1]=0.f; ff[r][2]=0.f; ff[r][3]=0.f; }

  for (int hc=0; hc<4; ++hc){
    __syncthreads();
    for (int k=0;k<16;++k){
      int idx = tid + (k<<8);
      int o = idx>>6, c = idx&63;
      w1s[wofs(o, c>>2) + (c&3)] = w1[(size_t)(hc*64+o)*64 + c];
      w2s[wofs(o, c>>2) + (c&3)] = w2[(size_t)o*256 + hc*64 + c];
    }
    __syncthreads();
    float hv[4][4];
    #pragma unroll
    for (int r=0;r<4;++r){ hv[r][0]=0.f; hv[r][1]=0.f; hv[r][2]=0.f; hv[r][3]=0.f; }
    #pragma unroll 4
    for (int c4=0;c4<16;++c4){
      float4 f[4], w[4];
      #pragma unroll
      for (int r=0;r<4;++r)  f[r] = *(const float4*)&f1l[(4*tr+r)*68 + (c4<<2)];
      #pragma unroll
      for (int oo=0;oo<4;++oo) w[oo] = *(const float4*)&w1s[wofs(4*to+oo, c4)];
      #pragma unroll
      for (int r=0;r<4;++r)
        #pragma unroll
        for (int oo=0;oo<4;++oo)
          hv[r][oo] += dot4(f[r], w[oo]);
    }
    #pragma unroll
    for (int r=0;r<4;++r){
      float4 v;
      float x0=hv[r][0], x1=hv[r][1], x2=hv[r][2], x3=hv[r][3];
      v.x = (x0>0.f)?x0:0.2f*x0; v.y = (x1>0.f)?x1:0.2f*x1;
      v.z = (x2>0.f)?x2:0.2f*x2; v.w = (x3>0.f)?x3:0.2f*x3;
      *(float4*)&hl[(4*tr+r)*68 + 4*to] = v;
    }
    __syncthreads();
    #pragma unroll 4
    for (int o4=0;o4<16;++o4){
      float4 h[4], w[4];
      #pragma unroll
      for (int r=0;r<4;++r)  h[r] = *(const float4*)&hl[(4*tr+r)*68 + (o4<<2)];
      #pragma unroll
      for (int oo=0;oo<4;++oo) w[oo] = *(const float4*)&w2s[wofs(4*to+oo, o4)];
      #pragma unroll
      for (int r=0;r<4;++r)
        #pragma unroll
        for (int oo=0;oo<4;++oo)
          ff[r][oo] += dot4(h[r], w[oo]);
    }
  }
  #pragma unroll
  for (int r=0;r<4;++r){
    float4 v;
    v.x = f1l[(4*tr+r)*68 + 4*to+0] + ff[r][0];
    v.y = f1l[(4*tr+r)*68 + 4*to+1] + ff[r][1];
    v.z = f1l[(4*tr+r)*68 + 4*to+2] + ff[r][2];
    v.w = f1l[(4*tr+r)*68 + 4*to+3] + ff[r][3];
    *(float4*)&t2[(rowBase + 4*tr + r)*64 + 4*to] = v;
  }
}

// ---------------------------------------------------------------- final BN2 + transpose
__global__ __launch_bounds__(256) void final_kernel(const float* __restrict__ t2,
    const float* __restrict__ bns, const float* __restrict__ bnq,
    const float* __restrict__ g2, const float* __restrict__ b2,
    float* __restrict__ out)
{
  __shared__ float tile[64*65];
  __shared__ float mu[64], rs[64], gg[64], bb[64];
  const int tid = threadIdx.x;
  const int b = blockIdx.y;
  const int n0 = blockIdx.x*64;
  if (tid < 64){
    float m = bns[tid] * (1.f/32768.f);
    float v = bnq[tid] * (1.f/32768.f) - m*m;
    mu[tid] = m; rs[tid] = 1.f/sqrtf(v + BN_EPS);
    gg[tid] = g2[tid]; bb[tid] = b2[tid];
  }
  __syncthreads();
  for (int k=0;k<16;++k){
    int idx = tid + (k<<8);
    int r = idx>>6, c = idx&63;
    float v = t2[((size_t)b*Ndim + n0 + r)*64 + c];
    tile[r*65+c] = (v - mu[c])*rs[c]*gg[c] + bb[c];
  }
  __syncthreads();
  for (int k=0;k<16;++k){
    int idx = tid + (k<<8);
    int c = idx>>6, nn = idx&63;
    out[((size_t)b*64 + c)*Ndim + n0 + nn] = tile[nn*65+c];
  }
}

extern "C" void kernel_launch(void* const* d_in, const int* in_sizes, int n_in,
                              void* d_out, int out_size, void* d_ws, size_t ws_size,
                              hipStream_t stream)
{
  (void)in_sizes; (void)n_in; (void)out_size; (void)ws_size;
  const float* x  = (const float*)d_in[0];
  const float* wq = (const float*)d_in[1];
  const float* wk = (const float*)d_in[2];
  const float* wv = (const float*)d_in[3];
  const float* w1 = (const float*)d_in[4];
  const float* w2 = (const float*)d_in[5];
  const float* g1 = (const float*)d_in[6];
  const float* b1 = (const float*)d_in[7];
  const float* g2 = (const float*)d_in[8];
  const float* b2 = (const float*)d_in[9];
  float* out = (float*)d_out;

  const size_t NE = (size_t)ROWS*64;
  float* feat = (float*)d_ws;
  float* sq   = feat + NE;
  float* Qb   = sq + ROWS;
  float* PKb  = Qb + NE;
  float* PVb  = PKb + NE;
  float* t1   = PVb + NE;
  float* t2   = t1 + NE;
  float* acc  = t2 + NE;   // 256 floats: bn1sum, bn1sq, bn2sum, bn2sq

  hipMemsetAsync(acc, 0, 256*sizeof(float), stream);
  prep_kernel<<<dim3(64,8), 256, 0, stream>>>(x, feat, sq);
  proj_kernel<<<dim3(512), 256, 0, stream>>>(feat, wq, wk, wv, Qb, PKb, PVb);
  knn_attn_kernel<<<dim3(4096), 512, 0, stream>>>(x, feat, sq, Qb, PKb, PVb, t1);
  bn_stats_kernel<<<dim3(256), 256, 0, stream>>>(t1, acc, acc+64);
  mlp_kernel<<<dim3(512), 256, 0, stream>>>(t1, w1, w2, g1, b1, acc, acc+64, t2);
  bn_stats_kernel<<<dim3(256), 256, 0, stream>>>(t2, acc+128, acc+192);
  final_kernel<<<dim3(64,8), 256, 0, stream>>>(t2, acc+128, acc+192, g2, b2, out);
}

// Round 8
// 463.419 us; speedup vs baseline: 3.6284x; 1.0317x over previous
//
#include <hip/hip_runtime.h>

#define Bdim 8
#define Cdim 64
#define Ndim 4096
#define Kdim 32
#define ROWS (Bdim*Ndim)   /* 32768 */
#define BN_EPS 1e-5f

__device__ __forceinline__ float dot4(float4 a, float4 b){
  return a.x*b.x + a.y*b.y + a.z*b.z + a.w*b.w;
}
__device__ __forceinline__ int wofs(int o, int g){ return o*64 + (((g ^ ((o>>2)&7)))<<2); }
__device__ __forceinline__ unsigned keyOf(float f){
  unsigned u = __float_as_uint(f);
  return (u & 0x80000000u) ? ~u : (u ^ 0x80000000u);
}

// ---------------------------------------------------------------- prep+proj fused
// x (B,C,N) -> transpose tile in LDS -> sq + Q/PK/PV projections.
// (feat buffer eliminated: knn reads its 8 query rows from x directly)
__global__ __launch_bounds__(256) void prep_proj_kernel(const float* __restrict__ x,
    const float* __restrict__ wq, const float* __restrict__ wk,
    const float* __restrict__ wv,
    float* __restrict__ sq,
    float* __restrict__ Qo, float* __restrict__ PKo, float* __restrict__ PVo)
{
  __shared__ __align__(16) float ftile[64*68];
  __shared__ __align__(16) float Ws[3][64*64];
  const int tid = threadIdx.x;
  const int blk = blockIdx.x;
  const int b  = blk & 7;
  const int n0 = (blk >> 3) * 64;
  // transposed load: coalesced global, 8-way LDS write conflict (acceptable, one-time)
  for (int k=0;k<16;++k){
    int idx = tid + (k<<8);
    int c = idx>>6, nn = idx&63;
    ftile[nn*68+c] = x[((size_t)b*64+c)*Ndim + n0 + nn];
  }
  {
    const float* wp[3] = {wq, wk, wv};
    for (int m=0;m<3;++m)
      for (int k=0;k<16;++k){
        int idx = tid + (k<<8);
        int o = idx>>6, c = idx&63;
        Ws[m][wofs(o, c>>2) + (c&3)] = wp[m][o*64 + c];
      }
  }
  __syncthreads();
  if (tid < 64){
    float a = 0.f;
    #pragma unroll
    for (int c=0;c<64;++c){ float v = ftile[tid*68+c]; a += v*v; }
    sq[b*Ndim + n0 + tid] = a;
  }
  const int tr = tid>>4, to = tid&15;
  const size_t rowBase = (size_t)b*Ndim + n0;
  float* outp[3] = {Qo, PKo, PVo};
  for (int m=0;m<3;++m){
    float acc[4][4];
    #pragma unroll
    for (int r=0;r<4;++r){ acc[r][0]=0.f; acc[r][1]=0.f; acc[r][2]=0.f; acc[r][3]=0.f; }
    #pragma unroll 4
    for (int c4=0;c4<16;++c4){
      float4 f[4], w[4];
      #pragma unroll
      for (int r=0;r<4;++r)  f[r] = *(const float4*)&ftile[(4*tr+r)*68 + (c4<<2)];
      #pragma unroll
      for (int oo=0;oo<4;++oo) w[oo] = *(const float4*)&Ws[m][wofs(4*to+oo, c4)];
      #pragma unroll
      for (int r=0;r<4;++r)
        #pragma unroll
        for (int oo=0;oo<4;++oo)
          acc[r][oo] += dot4(f[r], w[oo]);
    }
    #pragma unroll
    for (int r=0;r<4;++r){
      float4 v; v.x=acc[r][0]; v.y=acc[r][1]; v.z=acc[r][2]; v.w=acc[r][3];
      *(float4*)&outp[m][(rowBase + 4*tr + r)*64 + 4*to] = v;
    }
  }
}

// ---------------------------------------------------------------- knn + attention + BN1 stats
// 512 threads, 8 queries/WG. Coalesced x-based distances; per-wave exact
// top-32 (register keys, ballot threshold + bitonic). Epilogue computes t1
// AND accumulates per-channel BN1 sum/sumsq via block reduce + atomics.
__global__ __launch_bounds__(512, 4) void knn_attn_kernel(
    const float* __restrict__ x,
    const float* __restrict__ sq,
    const float* __restrict__ Qm, const float* __restrict__ PKm, const float* __restrict__ PVm,
    float* __restrict__ t1, float* __restrict__ bn1s, float* __restrict__ bn1q)
{
  __shared__ __align__(16) unsigned char smem[40992];
  float*    chunkF = (float*)smem;                 // [4][2048] 32 KB (distance phase)
  unsigned* candK  = (unsigned*)smem;              // [8][64]  (alias, selection)
  int*      candI  = (int*)(smem + 2048);          // [8][64]
  int*      outIdx = (int*)(smem + 4096);          // [8][32]
  float*    enS    = (float*)(smem + 5120);        // [8][128]
  float*    red1   = (float*)(smem + 5120);        // [512] (alias enS, after t1)
  float*    red2   = (float*)(smem + 7168);        // [512]
  float*    fnS    = (float*)(smem + 32768);       // [8][64]
  float*    qvS    = (float*)(smem + 34816);       // [8][64]
  float*    pknS   = (float*)(smem + 36864);       // [8][64]
  float*    pvnS   = (float*)(smem + 38912);       // [8][64]
  float*    sqnS   = (float*)(smem + 40960);       // [8]

  const int tid = threadIdx.x;
  const int lane = tid & 63;
  const int w = tid >> 6;
  const int blk = blockIdx.x;
  const int b  = blk & 7;                          // XCD-locality swizzle
  const int n0 = (blk >> 3) << 3;                  // 8 queries
  const float* xb = x + (size_t)b*64*Ndim;

  {
    int j = tid>>6, c = tid&63;
    size_t ro = ((size_t)b*Ndim + n0 + j)*64 + c;
    fnS[tid]  = xb[(size_t)c*Ndim + n0 + j];   // feat from x (transposed read)
    qvS[tid]  = Qm[ro];
    pknS[tid] = PKm[ro];
    pvnS[tid] = PVm[ro];
    if (tid < 8) sqnS[tid] = sq[b*Ndim + n0 + tid];
  }
  __syncthreads();

  unsigned kk[64];

  #pragma unroll
  for (int g=0; g<2; ++g){
    const int m0 = (g<<11) + (tid<<2);
    float acc[8][4];
    #pragma unroll
    for (int q=0;q<8;++q){ acc[q][0]=0.f; acc[q][1]=0.f; acc[q][2]=0.f; acc[q][3]=0.f; }
    #pragma unroll 8
    for (int c=0;c<64;++c){
      float4 xm = *(const float4*)&xb[(size_t)c*Ndim + m0];        // coalesced
      float4 qA = *(const float4*)&xb[(size_t)c*Ndim + n0];        // wave-uniform -> scalar
      float4 qB = *(const float4*)&xb[(size_t)c*Ndim + n0 + 4];
      const float qs[8] = {qA.x,qA.y,qA.z,qA.w,qB.x,qB.y,qB.z,qB.w};
      #pragma unroll
      for (int q=0;q<8;++q){
        acc[q][0] += qs[q]*xm.x; acc[q][1] += qs[q]*xm.y;
        acc[q][2] += qs[q]*xm.z; acc[q][3] += qs[q]*xm.w;
      }
    }
    float4 sqm4 = *(const float4*)&sq[b*Ndim + m0];
    #pragma unroll
    for (int half=0; half<2; ++half){
      __syncthreads();   // chunk free (or consumed by previous half)
      #pragma unroll
      for (int qq=0;qq<4;++qq){
        int q = (half<<2)+qq;
        float sqn_q = sqnS[q];
        float4 v;
        v.x = (2.f*acc[q][0]-sqn_q)-sqm4.x;
        v.y = (2.f*acc[q][1]-sqn_q)-sqm4.y;
        v.z = (2.f*acc[q][2]-sqn_q)-sqm4.z;
        v.w = (2.f*acc[q][3]-sqn_q)-sqm4.w;
        *(float4*)&chunkF[(qq<<11) + (tid<<2)] = v;
      }
      __syncthreads();
      if ((w>>2) == half){
        const int wq = w & 3;
        #pragma unroll
        for (int i=0;i<32;++i)
          kk[(g<<5)+i] = keyOf(chunkF[(wq<<11)+(i<<6)+lane]);
      }
    }
  }
  __syncthreads();   // chunk dead -> selection arrays may alias it

  // defensive pre-fill: unwritten slots stay VALID indices
  if (lane < 32) outIdx[(w<<5)+lane] = n0 + w;

  // ---- exact top-32, wave w handles query w, keys in registers
  {
    unsigned lmax = kk[0];
    #pragma unroll
    for (int j=1;j<64;++j) lmax = lmax > kk[j] ? lmax : kk[j];
    unsigned T = 0u;
    #pragma unroll
    for (int bit=31; bit>=0; --bit){
      unsigned cand = T | (1u << bit);
      int cnt = (int)__popcll(__ballot(lmax >= cand));
      if (cnt >= 32) T = cand;
    }
    int base = 0;
    #pragma unroll
    for (int j=0;j<64;++j){
      bool isc = (kk[j] >= T);
      unsigned long long mk = __ballot(isc);
      if (isc){
        int slot = base + (int)__popcll(mk & ((1ull<<lane)-1ull));
        if (slot < 64){
          candK[(w<<6)+slot] = kk[j];
          candI[(w<<6)+slot] = ((j>>5)<<11)+((j&31)<<6)+lane;
        }
      }
      base += (int)__popcll(mk);
    }
    const int S = base;   // >= 32 guaranteed
    __threadfence_block();
    if (S <= 64){
      unsigned long long C = 0ull;
      if (lane < S)
        C = ((unsigned long long)candK[(w<<6)+lane] << 32) |
            (unsigned long long)(~(unsigned)candI[(w<<6)+lane]);
      #pragma unroll
      for (int k2=2; k2<=64; k2<<=1){
        #pragma unroll
        for (int j2=k2>>1; j2>=1; j2>>=1){
          unsigned long long P = (unsigned long long)__shfl_xor((long long)C, j2, 64);
          bool lowIdx  = ((lane & j2) == 0);
          bool keepMax = (lowIdx == ((lane & k2) == 0));
          unsigned long long mx = C > P ? C : P;
          unsigned long long mn = C > P ? P : C;
          C = keepMax ? mx : mn;
        }
      }
      if (lane < 32) outIdx[(w<<5)+lane] = (int)(~(unsigned)(C & 0xFFFFFFFFull)) & (Ndim-1);
    } else {
      // rare fallback (register-only, fully unrolled)
      unsigned Te = 0u;
      for (int bit=31; bit>=0; --bit){
        unsigned cand = Te | (1u << bit);
        int lc = 0;
        #pragma unroll
        for (int j=0;j<64;++j) lc += (kk[j] >= cand) ? 1 : 0;
        #pragma unroll
        for (int off=1; off<64; off<<=1) lc += __shfl_xor(lc, off, 64);
        if (lc >= 32) Te = cand;
      }
      const unsigned long long below = (1ull << lane) - 1ull;
      int b2 = 0;
      #pragma unroll
      for (int j=0;j<64;++j){
        unsigned u = kk[j];
        unsigned long long mg = __ballot(u > Te);
        if (u > Te){
          int slot = b2 + (int)__popcll(mg & below);
          if (slot < 32) outIdx[(w<<5)+slot] = ((j>>5)<<11)+((j&31)<<6)+lane;
        }
        b2 += (int)__popcll(mg);
      }
      #pragma unroll
      for (int j=0;j<64;++j){
        unsigned u = kk[j];
        unsigned long long mt = __ballot(u == Te);
        if (u == Te){
          int slot = b2 + (int)__popcll(mt & below);
          if (slot < 32) outIdx[(w<<5)+slot] = ((j>>5)<<11)+((j&31)<<6)+lane;
        }
        b2 += (int)__popcll(mt);
      }
    }
  }
  __syncthreads();

  // ---- attention energies: 1024 tasks = 8q x 4h x 32k
  #pragma unroll
  for (int p=0;p<2;++p){
    int task = tid + (p<<9);
    int jn = task>>7, h = (task>>5)&3, k2 = task&31;
    int mj = outIdx[(jn<<5)+k2] & (Ndim-1);
    const float4* pk4 = (const float4*)(PKm + ((size_t)b*Ndim + mj)*64 + (h<<4));
    const float4* qq4 = (const float4*)&qvS[(jn<<6)+(h<<4)];
    const float4* nn4 = (const float4*)&pknS[(jn<<6)+(h<<4)];
    float e = 0.f;
    #pragma unroll
    for (int d=0;d<4;++d){
      float4 kv = pk4[d], qq = qq4[d], nn = nn4[d];
      e += qq.x*(kv.x-nn.x) + qq.y*(kv.y-nn.y) + qq.z*(kv.z-nn.z) + qq.w*(kv.w-nn.w);
    }
    enS[(jn<<7)+(h<<5)+k2] = e * 0.25f;
  }
  __syncthreads();
  if (tid < 32){
    int jn = tid>>2, h = tid&3;
    float* ep = &enS[(jn<<7)+(h<<5)];
    float mx = -1e30f;
    for (int k2=0;k2<32;++k2) mx = fmaxf(mx, ep[k2]);
    float ssum = 0.f;
    for (int k2=0;k2<32;++k2){ float ex = expf(ep[k2]-mx); ep[k2] = ex; ssum += ex; }
    float inv = 1.f/ssum;
    for (int k2=0;k2<32;++k2) ep[k2] *= inv;
  }
  __syncthreads();
  float tval;
  {
    int jn = tid>>6, c = tid&63, h = c>>4;
    float a2 = 0.f;
    #pragma unroll 8
    for (int k2=0;k2<32;++k2){
      int mj = outIdx[(jn<<5)+k2] & (Ndim-1);
      a2 += enS[(jn<<7)+(h<<5)+k2] * (PVm[((size_t)b*Ndim + mj)*64 + c] - pvnS[(jn<<6)+c]);
    }
    tval = fnS[(jn<<6)+c] + a2;
    t1[((size_t)b*Ndim + n0 + jn)*64 + c] = tval;
  }
  // ---- fused BN1 stats: per-channel sum/sumsq over this WG's 8 rows
  __syncthreads();            // enS fully consumed -> red1/red2 may alias
  red1[tid] = tval;
  red2[tid] = tval*tval;
  __syncthreads();
  if (tid < 64){
    float S = 0.f, S2 = 0.f;
    #pragma unroll
    for (int j=0;j<8;++j){ S += red1[(j<<6)+tid]; S2 += red2[(j<<6)+tid]; }
    atomicAdd(&bn1s[tid], S);
    atomicAdd(&bn1q[tid], S2);
  }
}

// ---------------------------------------------------------------- MLP + BN2 stats
// f1 = BN1(t1); hid = leaky(f1@w1^T); t2 = f1 + hid@w2^T; accumulate BN2 stats
__global__ __launch_bounds__(256) void mlp_kernel(const float* __restrict__ t1,
    const float* __restrict__ w1, const float* __restrict__ w2,
    const float* __restrict__ g1, const float* __restrict__ b1,
    const float* __restrict__ bns, const float* __restrict__ bnq,
    float* __restrict__ t2, float* __restrict__ bn2s, float* __restrict__ bn2q)
{
  __shared__ __align__(16) float f1l[64*68];
  __shared__ __align__(16) float hl[64*68];
  __shared__ __align__(16) float w1s[64*64];
  __shared__ __align__(16) float w2s[64*64];
  __shared__ float mu[64], rs[64], gg[64], bb[64];
  const int tid = threadIdx.x;
  if (tid < 64){
    float m = bns[tid] * (1.f/32768.f);
    float v = bnq[tid] * (1.f/32768.f) - m*m;
    mu[tid] = m; rs[tid] = 1.f/sqrtf(v + BN_EPS);
    gg[tid] = g1[tid]; bb[tid] = b1[tid];
  }
  __syncthreads();
  const size_t rowBase = (size_t)blockIdx.x*64;
  for (int k=0;k<16;++k){
    int idx = tid + (k<<8);
    int r = idx>>6, c = idx&63;
    float v = t1[(rowBase + r)*64 + c];
    f1l[r*68+c] = (v - mu[c])*rs[c]*gg[c] + bb[c];
  }
  const int tr = tid>>4, to = tid&15;
  float ff[4][4];
  #pragma unroll
  for (int r=0;r<4;++r){ ff[r][0]=0.f; ff[r][1]=0.f; ff[r][2]=0.f; ff[r][3]=0.f; }

  for (int hc=0; hc<4; ++hc){
    __syncthreads();
    for (int k=0;k<16;++k){
      int idx = tid + (k<<8);
      int o = idx>>6, c = idx&63;
      w1s[wofs(o, c>>2) + (c&3)] = w1[(size_t)(hc*64+o)*64 + c];
      w2s[wofs(o, c>>2) + (c&3)] = w2[(size_t)o*256 + hc*64 + c];
    }
    __syncthreads();
    float hv[4][4];
    #pragma unroll
    for (int r=0;r<4;++r){ hv[r][0]=0.f; hv[r][1]=0.f; hv[r][2]=0.f; hv[r][3]=0.f; }
    #pragma unroll 4
    for (int c4=0;c4<16;++c4){
      float4 f[4], w[4];
      #pragma unroll
      for (int r=0;r<4;++r)  f[r] = *(const float4*)&f1l[(4*tr+r)*68 + (c4<<2)];
      #pragma unroll
      for (int oo=0;oo<4;++oo) w[oo] = *(const float4*)&w1s[wofs(4*to+oo, c4)];
      #pragma unroll
      for (int r=0;r<4;++r)
        #pragma unroll
        for (int oo=0;oo<4;++oo)
          hv[r][oo] += dot4(f[r], w[oo]);
    }
    #pragma unroll
    for (int r=0;r<4;++r){
      float4 v;
      float x0=hv[r][0], x1=hv[r][1], x2=hv[r][2], x3=hv[r][3];
      v.x = (x0>0.f)?x0:0.2f*x0; v.y = (x1>0.f)?x1:0.2f*x1;
      v.z = (x2>0.f)?x2:0.2f*x2; v.w = (x3>0.f)?x3:0.2f*x3;
      *(float4*)&hl[(4*tr+r)*68 + 4*to] = v;
    }
    __syncthreads();
    #pragma unroll 4
    for (int o4=0;o4<16;++o4){
      float4 h[4], w[4];
      #pragma unroll
      for (int r=0;r<4;++r)  h[r] = *(const float4*)&hl[(4*tr+r)*68 + (o4<<2)];
      #pragma unroll
      for (int oo=0;oo<4;++oo) w[oo] = *(const float4*)&w2s[wofs(4*to+oo, o4)];
      #pragma unroll
      for (int r=0;r<4;++r)
        #pragma unroll
        for (int oo=0;oo<4;++oo)
          ff[r][oo] += dot4(h[r], w[oo]);
    }
  }
  float ls[4]  = {0.f,0.f,0.f,0.f};
  float ls2[4] = {0.f,0.f,0.f,0.f};
  #pragma unroll
  for (int r=0;r<4;++r){
    float4 v;
    v.x = f1l[(4*tr+r)*68 + 4*to+0] + ff[r][0];
    v.y = f1l[(4*tr+r)*68 + 4*to+1] + ff[r][1];
    v.z = f1l[(4*tr+r)*68 + 4*to+2] + ff[r][2];
    v.w = f1l[(4*tr+r)*68 + 4*to+3] + ff[r][3];
    *(float4*)&t2[(rowBase + 4*tr + r)*64 + 4*to] = v;
    ls[0]+=v.x; ls[1]+=v.y; ls[2]+=v.z; ls[3]+=v.w;
    ls2[0]+=v.x*v.x; ls2[1]+=v.y*v.y; ls2[2]+=v.z*v.z; ls2[3]+=v.w*v.w;
  }
  // ---- fused BN2 stats (reuse hl after all GEMM reads done)
  __syncthreads();
  #pragma unroll
  for (int i=0;i<4;++i){
    hl[tr*64 + 4*to + i]        = ls[i];
    hl[1024 + tr*64 + 4*to + i] = ls2[i];
  }
  __syncthreads();
  if (tid < 64){
    float S = 0.f, S2 = 0.f;
    #pragma unroll
    for (int g2=0; g2<16; ++g2){ S += hl[g2*64 + tid]; S2 += hl[1024 + g2*64 + tid]; }
    atomicAdd(&bn2s[tid], S);
    atomicAdd(&bn2q[tid], S2);
  }
}

// ---------------------------------------------------------------- final BN2 + transpose
__global__ __launch_bounds__(256) void final_kernel(const float* __restrict__ t2,
    const float* __restrict__ bns, const float* __restrict__ bnq,
    const float* __restrict__ g2, const float* __restrict__ b2,
    float* __restrict__ out)
{
  __shared__ float tile[64*65];
  __shared__ float mu[64], rs[64], gg[64], bb[64];
  const int tid = threadIdx.x;
  const int b = blockIdx.y;
  const int n0 = blockIdx.x*64;
  if (tid < 64){
    float m = bns[tid] * (1.f/32768.f);
    float v = bnq[tid] * (1.f/32768.f) - m*m;
    mu[tid] = m; rs[tid] = 1.f/sqrtf(v + BN_EPS);
    gg[tid] = g2[tid]; bb[tid] = b2[tid];
  }
  __syncthreads();
  for (int k=0;k<16;++k){
    int idx = tid + (k<<8);
    int r = idx>>6, c = idx&63;
    float v = t2[((size_t)b*Ndim + n0 + r)*64 + c];
    tile[r*65+c] = (v - mu[c])*rs[c]*gg[c] + bb[c];
  }
  __syncthreads();
  for (int k=0;k<16;++k){
    int idx = tid + (k<<8);
    int c = idx>>6, nn = idx&63;
    out[((size_t)b*64 + c)*Ndim + n0 + nn] = tile[nn*65+c];
  }
}

extern "C" void kernel_launch(void* const* d_in, const int* in_sizes, int n_in,
                              void* d_out, int out_size, void* d_ws, size_t ws_size,
                              hipStream_t stream)
{
  (void)in_sizes; (void)n_in; (void)out_size; (void)ws_size;
  const float* x  = (const float*)d_in[0];
  const float* wq = (const float*)d_in[1];
  const float* wk = (const float*)d_in[2];
  const float* wv = (const float*)d_in[3];
  const float* w1 = (const float*)d_in[4];
  const float* w2 = (const float*)d_in[5];
  const float* g1 = (const float*)d_in[6];
  const float* b1 = (const float*)d_in[7];
  const float* g2 = (const float*)d_in[8];
  const float* b2 = (const float*)d_in[9];
  float* out = (float*)d_out;

  const size_t NE = (size_t)ROWS*64;
  float* sq   = (float*)d_ws;
  float* Qb   = sq + ROWS;
  float* PKb  = Qb + NE;
  float* PVb  = PKb + NE;
  float* t1   = PVb + NE;
  float* t2   = t1 + NE;
  float* acc  = t2 + NE;   // 256 floats: bn1sum, bn1sq, bn2sum, bn2sq

  hipMemsetAsync(acc, 0, 256*sizeof(float), stream);
  prep_proj_kernel<<<dim3(512), 256, 0, stream>>>(x, wq, wk, wv, sq, Qb, PKb, PVb);
  knn_attn_kernel<<<dim3(4096), 512, 0, stream>>>(x, sq, Qb, PKb, PVb, t1, acc, acc+64);
  mlp_kernel<<<dim3(512), 256, 0, stream>>>(t1, w1, w2, g1, b1, acc, acc+64, t2, acc+128, acc+192);
  final_kernel<<<dim3(64,8), 256, 0, stream>>>(t2, acc+128, acc+192, g2, b2, out);
}

// Round 9
// 444.893 us; speedup vs baseline: 3.7794x; 1.0416x over previous
//
#include <hip/hip_runtime.h>

#define Bdim 8
#define Cdim 64
#define Ndim 4096
#define Kdim 32
#define ROWS (Bdim*Ndim)   /* 32768 */
#define BN_EPS 1e-5f

__device__ __forceinline__ float dot4(float4 a, float4 b){
  return a.x*b.x + a.y*b.y + a.z*b.z + a.w*b.w;
}
__device__ __forceinline__ int wofs(int o, int g){ return o*64 + (((g ^ ((o>>2)&7)))<<2); }
__device__ __forceinline__ unsigned keyOf(float f){
  unsigned u = __float_as_uint(f);
  return (u & 0x80000000u) ? ~u : (u ^ 0x80000000u);
}

// ---------------------------------------------------------------- prep+proj fused
// x (B,C,N) -> transpose tile in LDS -> sq + Q/PK/PV projections.
// Block 0 also zeroes the BN accumulators (replaces a memset dispatch).
__global__ __launch_bounds__(256) void prep_proj_kernel(const float* __restrict__ x,
    const float* __restrict__ wq, const float* __restrict__ wk,
    const float* __restrict__ wv,
    float* __restrict__ sq,
    float* __restrict__ Qo, float* __restrict__ PKo, float* __restrict__ PVo,
    float* __restrict__ accZ)
{
  __shared__ __align__(16) float ftile[64*68];
  __shared__ __align__(16) float Ws[3][64*64];
  const int tid = threadIdx.x;
  const int blk = blockIdx.x;
  const int b  = blk & 7;
  const int n0 = (blk >> 3) * 64;
  if (blk == 0) accZ[tid] = 0.f;   // 256 floats: bn1s, bn1q, bn2s, bn2q
  // transposed load: coalesced global, 8-way LDS write conflict (one-time)
  for (int k=0;k<16;++k){
    int idx = tid + (k<<8);
    int c = idx>>6, nn = idx&63;
    ftile[nn*68+c] = x[((size_t)b*64+c)*Ndim + n0 + nn];
  }
  {
    const float* wp[3] = {wq, wk, wv};
    for (int m=0;m<3;++m)
      for (int k=0;k<16;++k){
        int idx = tid + (k<<8);
        int o = idx>>6, c = idx&63;
        Ws[m][wofs(o, c>>2) + (c&3)] = wp[m][o*64 + c];
      }
  }
  __syncthreads();
  if (tid < 64){
    float a = 0.f;
    #pragma unroll
    for (int c=0;c<64;++c){ float v = ftile[tid*68+c]; a += v*v; }
    sq[b*Ndim + n0 + tid] = a;
  }
  const int tr = tid>>4, to = tid&15;
  const size_t rowBase = (size_t)b*Ndim + n0;
  float* outp[3] = {Qo, PKo, PVo};
  for (int m=0;m<3;++m){
    float acc[4][4];
    #pragma unroll
    for (int r=0;r<4;++r){ acc[r][0]=0.f; acc[r][1]=0.f; acc[r][2]=0.f; acc[r][3]=0.f; }
    #pragma unroll 4
    for (int c4=0;c4<16;++c4){
      float4 f[4], w[4];
      #pragma unroll
      for (int r=0;r<4;++r)  f[r] = *(const float4*)&ftile[(4*tr+r)*68 + (c4<<2)];
      #pragma unroll
      for (int oo=0;oo<4;++oo) w[oo] = *(const float4*)&Ws[m][wofs(4*to+oo, c4)];
      #pragma unroll
      for (int r=0;r<4;++r)
        #pragma unroll
        for (int oo=0;oo<4;++oo)
          acc[r][oo] += dot4(f[r], w[oo]);
    }
    #pragma unroll
    for (int r=0;r<4;++r){
      float4 v; v.x=acc[r][0]; v.y=acc[r][1]; v.z=acc[r][2]; v.w=acc[r][3];
      *(float4*)&outp[m][(rowBase + 4*tr + r)*64 + 4*to] = v;
    }
  }
}

// ---------------------------------------------------------------- knn + attention + BN1 stats
__global__ __launch_bounds__(512, 4) void knn_attn_kernel(
    const float* __restrict__ x,
    const float* __restrict__ sq,
    const float* __restrict__ Qm, const float* __restrict__ PKm, const float* __restrict__ PVm,
    float* __restrict__ t1, float* __restrict__ bn1s, float* __restrict__ bn1q)
{
  __shared__ __align__(16) unsigned char smem[40992];
  float*    chunkF = (float*)smem;                 // [4][2048] 32 KB (distance phase)
  unsigned* candK  = (unsigned*)smem;              // [8][64]  (alias, selection)
  int*      candI  = (int*)(smem + 2048);          // [8][64]
  int*      outIdx = (int*)(smem + 4096);          // [8][32]
  float*    enS    = (float*)(smem + 5120);        // [8][128]
  float*    red1   = (float*)(smem + 5120);        // [512] (alias enS, after t1)
  float*    red2   = (float*)(smem + 7168);        // [512]
  float*    fnS    = (float*)(smem + 32768);       // [8][64]
  float*    qvS    = (float*)(smem + 34816);       // [8][64]
  float*    pknS   = (float*)(smem + 36864);       // [8][64]
  float*    pvnS   = (float*)(smem + 38912);       // [8][64]
  float*    sqnS   = (float*)(smem + 40960);       // [8]

  const int tid = threadIdx.x;
  const int lane = tid & 63;
  const int w = tid >> 6;
  const int blk = blockIdx.x;
  const int b  = blk & 7;                          // XCD-locality swizzle
  const int n0 = (blk >> 3) << 3;                  // 8 queries
  const float* xb = x + (size_t)b*64*Ndim;

  {
    int j = tid>>6, c = tid&63;
    size_t ro = ((size_t)b*Ndim + n0 + j)*64 + c;
    fnS[tid]  = xb[(size_t)c*Ndim + n0 + j];   // feat from x (transposed read)
    qvS[tid]  = Qm[ro];
    pknS[tid] = PKm[ro];
    pvnS[tid] = PVm[ro];
    if (tid < 8) sqnS[tid] = sq[b*Ndim + n0 + tid];
  }
  __syncthreads();

  unsigned kk[64];

  #pragma unroll
  for (int g=0; g<2; ++g){
    const int m0 = (g<<11) + (tid<<2);
    float acc[8][4];
    #pragma unroll
    for (int q=0;q<8;++q){ acc[q][0]=0.f; acc[q][1]=0.f; acc[q][2]=0.f; acc[q][3]=0.f; }
    #pragma unroll 4
    for (int c=0;c<64;++c){
      float4 xm = *(const float4*)&xb[(size_t)c*Ndim + m0];        // coalesced
      float4 qA = *(const float4*)&xb[(size_t)c*Ndim + n0];        // wave-uniform -> scalar
      float4 qB = *(const float4*)&xb[(size_t)c*Ndim + n0 + 4];
      const float qs[8] = {qA.x,qA.y,qA.z,qA.w,qB.x,qB.y,qB.z,qB.w};
      #pragma unroll
      for (int q=0;q<8;++q){
        acc[q][0] += qs[q]*xm.x; acc[q][1] += qs[q]*xm.y;
        acc[q][2] += qs[q]*xm.z; acc[q][3] += qs[q]*xm.w;
      }
    }
    float4 sqm4 = *(const float4*)&sq[b*Ndim + m0];
    #pragma unroll
    for (int half=0; half<2; ++half){
      __syncthreads();   // chunk free (or consumed by previous half)
      #pragma unroll
      for (int qq=0;qq<4;++qq){
        int q = (half<<2)+qq;
        float sqn_q = sqnS[q];
        float4 v;
        v.x = (2.f*acc[q][0]-sqn_q)-sqm4.x;
        v.y = (2.f*acc[q][1]-sqn_q)-sqm4.y;
        v.z = (2.f*acc[q][2]-sqn_q)-sqm4.z;
        v.w = (2.f*acc[q][3]-sqn_q)-sqm4.w;
        *(float4*)&chunkF[(qq<<11) + (tid<<2)] = v;
      }
      __syncthreads();
      if ((w>>2) == half){
        const int wq = w & 3;
        #pragma unroll
        for (int i=0;i<32;++i)
          kk[(g<<5)+i] = keyOf(chunkF[(wq<<11)+(i<<6)+lane]);
      }
    }
  }
  __syncthreads();   // chunk dead -> selection arrays may alias it

  // defensive pre-fill: unwritten slots stay VALID indices
  if (lane < 32) outIdx[(w<<5)+lane] = n0 + w;

  // ---- exact top-32, wave w handles query w, keys in registers
  {
    unsigned lmax = kk[0];
    #pragma unroll
    for (int j=1;j<64;++j) lmax = lmax > kk[j] ? lmax : kk[j];
    unsigned T = 0u;
    #pragma unroll
    for (int bit=31; bit>=0; --bit){
      unsigned cand = T | (1u << bit);
      int cnt = (int)__popcll(__ballot(lmax >= cand));
      if (cnt >= 32) T = cand;
    }
    int base = 0;
    #pragma unroll
    for (int j=0;j<64;++j){
      bool isc = (kk[j] >= T);
      unsigned long long mk = __ballot(isc);
      if (isc){
        int slot = base + (int)__popcll(mk & ((1ull<<lane)-1ull));
        if (slot < 64){
          candK[(w<<6)+slot] = kk[j];
          candI[(w<<6)+slot] = ((j>>5)<<11)+((j&31)<<6)+lane;
        }
      }
      base += (int)__popcll(mk);
    }
    const int S = base;   // >= 32 guaranteed
    __threadfence_block();
    if (S <= 64){
      unsigned long long C = 0ull;
      if (lane < S)
        C = ((unsigned long long)candK[(w<<6)+lane] << 32) |
            (unsigned long long)(~(unsigned)candI[(w<<6)+lane]);
      #pragma unroll
      for (int k2=2; k2<=64; k2<<=1){
        #pragma unroll
        for (int j2=k2>>1; j2>=1; j2>>=1){
          unsigned long long P = (unsigned long long)__shfl_xor((long long)C, j2, 64);
          bool lowIdx  = ((lane & j2) == 0);
          bool keepMax = (lowIdx == ((lane & k2) == 0));
          unsigned long long mx = C > P ? C : P;
          unsigned long long mn = C > P ? P : C;
          C = keepMax ? mx : mn;
        }
      }
      if (lane < 32) outIdx[(w<<5)+lane] = (int)(~(unsigned)(C & 0xFFFFFFFFull)) & (Ndim-1);
    } else {
      // rare fallback (register-only, fully unrolled)
      unsigned Te = 0u;
      for (int bit=31; bit>=0; --bit){
        unsigned cand = Te | (1u << bit);
        int lc = 0;
        #pragma unroll
        for (int j=0;j<64;++j) lc += (kk[j] >= cand) ? 1 : 0;
        #pragma unroll
        for (int off=1; off<64; off<<=1) lc += __shfl_xor(lc, off, 64);
        if (lc >= 32) Te = cand;
      }
      const unsigned long long below = (1ull << lane) - 1ull;
      int b2 = 0;
      #pragma unroll
      for (int j=0;j<64;++j){
        unsigned u = kk[j];
        unsigned long long mg = __ballot(u > Te);
        if (u > Te){
          int slot = b2 + (int)__popcll(mg & below);
          if (slot < 32) outIdx[(w<<5)+slot] = ((j>>5)<<11)+((j&31)<<6)+lane;
        }
        b2 += (int)__popcll(mg);
      }
      #pragma unroll
      for (int j=0;j<64;++j){
        unsigned u = kk[j];
        unsigned long long mt = __ballot(u == Te);
        if (u == Te){
          int slot = b2 + (int)__popcll(mt & below);
          if (slot < 32) outIdx[(w<<5)+slot] = ((j>>5)<<11)+((j&31)<<6)+lane;
        }
        b2 += (int)__popcll(mt);
      }
    }
  }
  __syncthreads();

  // ---- attention energies: 1024 tasks = 8q x 4h x 32k
  #pragma unroll
  for (int p=0;p<2;++p){
    int task = tid + (p<<9);
    int jn = task>>7, h = (task>>5)&3, k2 = task&31;
    int mj = outIdx[(jn<<5)+k2] & (Ndim-1);
    const float4* pk4 = (const float4*)(PKm + ((size_t)b*Ndim + mj)*64 + (h<<4));
    const float4* qq4 = (const float4*)&qvS[(jn<<6)+(h<<4)];
    const float4* nn4 = (const float4*)&pknS[(jn<<6)+(h<<4)];
    float e = 0.f;
    #pragma unroll
    for (int d=0;d<4;++d){
      float4 kv = pk4[d], qq = qq4[d], nn = nn4[d];
      e += qq.x*(kv.x-nn.x) + qq.y*(kv.y-nn.y) + qq.z*(kv.z-nn.z) + qq.w*(kv.w-nn.w);
    }
    enS[(jn<<7)+(h<<5)+k2] = e * 0.25f;
  }
  __syncthreads();
  if (tid < 32){
    int jn = tid>>2, h = tid&3;
    float* ep = &enS[(jn<<7)+(h<<5)];
    float mx = -1e30f;
    for (int k2=0;k2<32;++k2) mx = fmaxf(mx, ep[k2]);
    float ssum = 0.f;
    for (int k2=0;k2<32;++k2){ float ex = expf(ep[k2]-mx); ep[k2] = ex; ssum += ex; }
    float inv = 1.f/ssum;
    for (int k2=0;k2<32;++k2) ep[k2] *= inv;
  }
  __syncthreads();
  float tval;
  {
    int jn = tid>>6, c = tid&63, h = c>>4;
    float a2 = 0.f;
    #pragma unroll 8
    for (int k2=0;k2<32;++k2){
      int mj = outIdx[(jn<<5)+k2] & (Ndim-1);
      a2 += enS[(jn<<7)+(h<<5)+k2] * (PVm[((size_t)b*Ndim + mj)*64 + c] - pvnS[(jn<<6)+c]);
    }
    tval = fnS[(jn<<6)+c] + a2;
    t1[((size_t)b*Ndim + n0 + jn)*64 + c] = tval;
  }
  // ---- fused BN1 stats: per-channel sum/sumsq over this WG's 8 rows
  __syncthreads();            // enS fully consumed -> red1/red2 may alias
  red1[tid] = tval;
  red2[tid] = tval*tval;
  __syncthreads();
  if (tid < 64){
    float S = 0.f, S2 = 0.f;
    #pragma unroll
    for (int j=0;j<8;++j){ S += red1[(j<<6)+tid]; S2 += red2[(j<<6)+tid]; }
    atomicAdd(&bn1s[tid], S);
    atomicAdd(&bn1q[tid], S2);
  }
}

// ---------------------------------------------------------------- MLP + BN2 stats
__global__ __launch_bounds__(256) void mlp_kernel(const float* __restrict__ t1,
    const float* __restrict__ w1, const float* __restrict__ w2,
    const float* __restrict__ g1, const float* __restrict__ b1,
    const float* __restrict__ bns, const float* __restrict__ bnq,
    float* __restrict__ t2, float* __restrict__ bn2s, float* __restrict__ bn2q)
{
  __shared__ __align__(16) float f1l[64*68];
  __shared__ __align__(16) float hl[64*68];
  __shared__ __align__(16) float w1s[64*64];
  __shared__ __align__(16) float w2s[64*64];
  __shared__ float mu[64], rs[64], gg[64], bb[64];
  const int tid = threadIdx.x;
  if (tid < 64){
    float m = bns[tid] * (1.f/32768.f);
    float v = bnq[tid] * (1.f/32768.f) - m*m;
    mu[tid] = m; rs[tid] = 1.f/sqrtf(v + BN_EPS);
    gg[tid] = g1[tid]; bb[tid] = b1[tid];
  }
  __syncthreads();
  const size_t rowBase = (size_t)blockIdx.x*64;
  for (int k=0;k<16;++k){
    int idx = tid + (k<<8);
    int r = idx>>6, c = idx&63;
    float v = t1[(rowBase + r)*64 + c];
    f1l[r*68+c] = (v - mu[c])*rs[c]*gg[c] + bb[c];
  }
  const int tr = tid>>4, to = tid&15;
  float ff[4][4];
  #pragma unroll
  for (int r=0;r<4;++r){ ff[r][0]=0.f; ff[r][1]=0.f; ff[r][2]=0.f; ff[r][3]=0.f; }

  for (int hc=0; hc<4; ++hc){
    __syncthreads();
    for (int k=0;k<16;++k){
      int idx = tid + (k<<8);
      int o = idx>>6, c = idx&63;
      w1s[wofs(o, c>>2) + (c&3)] = w1[(size_t)(hc*64+o)*64 + c];
      w2s[wofs(o, c>>2) + (c&3)] = w2[(size_t)o*256 + hc*64 + c];
    }
    __syncthreads();
    float hv[4][4];
    #pragma unroll
    for (int r=0;r<4;++r){ hv[r][0]=0.f; hv[r][1]=0.f; hv[r][2]=0.f; hv[r][3]=0.f; }
    #pragma unroll 4
    for (int c4=0;c4<16;++c4){
      float4 f[4], w[4];
      #pragma unroll
      for (int r=0;r<4;++r)  f[r] = *(const float4*)&f1l[(4*tr+r)*68 + (c4<<2)];
      #pragma unroll
      for (int oo=0;oo<4;++oo) w[oo] = *(const float4*)&w1s[wofs(4*to+oo, c4)];
      #pragma unroll
      for (int r=0;r<4;++r)
        #pragma unroll
        for (int oo=0;oo<4;++oo)
          hv[r][oo] += dot4(f[r], w[oo]);
    }
    #pragma unroll
    for (int r=0;r<4;++r){
      float4 v;
      float x0=hv[r][0], x1=hv[r][1], x2=hv[r][2], x3=hv[r][3];
      v.x = (x0>0.f)?x0:0.2f*x0; v.y = (x1>0.f)?x1:0.2f*x1;
      v.z = (x2>0.f)?x2:0.2f*x2; v.w = (x3>0.f)?x3:0.2f*x3;
      *(float4*)&hl[(4*tr+r)*68 + 4*to] = v;
    }
    __syncthreads();
    #pragma unroll 4
    for (int o4=0;o4<16;++o4){
      float4 h[4], w[4];
      #pragma unroll
      for (int r=0;r<4;++r)  h[r] = *(const float4*)&hl[(4*tr+r)*68 + (o4<<2)];
      #pragma unroll
      for (int oo=0;oo<4;++oo) w[oo] = *(const float4*)&w2s[wofs(4*to+oo, o4)];
      #pragma unroll
      for (int r=0;r<4;++r)
        #pragma unroll
        for (int oo=0;oo<4;++oo)
          ff[r][oo] += dot4(h[r], w[oo]);
    }
  }
  float ls[4]  = {0.f,0.f,0.f,0.f};
  float ls2[4] = {0.f,0.f,0.f,0.f};
  #pragma unroll
  for (int r=0;r<4;++r){
    float4 v;
    v.x = f1l[(4*tr+r)*68 + 4*to+0] + ff[r][0];
    v.y = f1l[(4*tr+r)*68 + 4*to+1] + ff[r][1];
    v.z = f1l[(4*tr+r)*68 + 4*to+2] + ff[r][2];
    v.w = f1l[(4*tr+r)*68 + 4*to+3] + ff[r][3];
    *(float4*)&t2[(rowBase + 4*tr + r)*64 + 4*to] = v;
    ls[0]+=v.x; ls[1]+=v.y; ls[2]+=v.z; ls[3]+=v.w;
    ls2[0]+=v.x*v.x; ls2[1]+=v.y*v.y; ls2[2]+=v.z*v.z; ls2[3]+=v.w*v.w;
  }
  __syncthreads();
  #pragma unroll
  for (int i=0;i<4;++i){
    hl[tr*64 + 4*to + i]        = ls[i];
    hl[1024 + tr*64 + 4*to + i] = ls2[i];
  }
  __syncthreads();
  if (tid < 64){
    float S = 0.f, S2 = 0.f;
    #pragma unroll
    for (int g2=0; g2<16; ++g2){ S += hl[g2*64 + tid]; S2 += hl[1024 + g2*64 + tid]; }
    atomicAdd(&bn2s[tid], S);
    atomicAdd(&bn2q[tid], S2);
  }
}

// ---------------------------------------------------------------- final BN2 + transpose
__global__ __launch_bounds__(256) void final_kernel(const float* __restrict__ t2,
    const float* __restrict__ bns, const float* __restrict__ bnq,
    const float* __restrict__ g2, const float* __restrict__ b2,
    float* __restrict__ out)
{
  __shared__ float tile[64*65];
  __shared__ float mu[64], rs[64], gg[64], bb[64];
  const int tid = threadIdx.x;
  const int b = blockIdx.y;
  const int n0 = blockIdx.x*64;
  if (tid < 64){
    float m = bns[tid] * (1.f/32768.f);
    float v = bnq[tid] * (1.f/32768.f) - m*m;
    mu[tid] = m; rs[tid] = 1.f/sqrtf(v + BN_EPS);
    gg[tid] = g2[tid]; bb[tid] = b2[tid];
  }
  __syncthreads();
  for (int k=0;k<16;++k){
    int idx = tid + (k<<8);
    int r = idx>>6, c = idx&63;
    float v = t2[((size_t)b*Ndim + n0 + r)*64 + c];
    tile[r*65+c] = (v - mu[c])*rs[c]*gg[c] + bb[c];
  }
  __syncthreads();
  for (int k=0;k<16;++k){
    int idx = tid + (k<<8);
    int c = idx>>6, nn = idx&63;
    out[((size_t)b*64 + c)*Ndim + n0 + nn] = tile[nn*65+c];
  }
}

extern "C" void kernel_launch(void* const* d_in, const int* in_sizes, int n_in,
                              void* d_out, int out_size, void* d_ws, size_t ws_size,
                              hipStream_t stream)
{
  (void)in_sizes; (void)n_in; (void)out_size; (void)ws_size;
  const float* x  = (const float*)d_in[0];
  const float* wq = (const float*)d_in[1];
  const float* wk = (const float*)d_in[2];
  const float* wv = (const float*)d_in[3];
  const float* w1 = (const float*)d_in[4];
  const float* w2 = (const float*)d_in[5];
  const float* g1 = (const float*)d_in[6];
  const float* b1 = (const float*)d_in[7];
  const float* g2 = (const float*)d_in[8];
  const float* b2 = (const float*)d_in[9];
  float* out = (float*)d_out;

  const size_t NE = (size_t)ROWS*64;
  float* sq   = (float*)d_ws;
  float* Qb   = sq + ROWS;
  float* PKb  = Qb + NE;
  float* PVb  = PKb + NE;
  float* t1   = PVb + NE;
  float* t2   = t1 + NE;
  float* acc  = t2 + NE;   // 256 floats: bn1sum, bn1sq, bn2sum, bn2sq

  prep_proj_kernel<<<dim3(512), 256, 0, stream>>>(x, wq, wk, wv, sq, Qb, PKb, PVb, acc);
  knn_attn_kernel<<<dim3(4096), 512, 0, stream>>>(x, sq, Qb, PKb, PVb, t1, acc, acc+64);
  mlp_kernel<<<dim3(512), 256, 0, stream>>>(t1, w1, w2, g1, b1, acc, acc+64, t2, acc+128, acc+192);
  final_kernel<<<dim3(64,8), 256, 0, stream>>>(t2, acc+128, acc+192, g2, b2, out);
}